// Round 7
// baseline (563.323 us; speedup 1.0000x reference)
//
#include <hip/hip_runtime.h>
#include <hip/hip_bf16.h>

#define BB 16
#define NPG 512
#define CC 128
#define HH 8
#define LL 4
#define FFN 512
#define NCLS 4
#define DD 16
#define TT 513            // NPG + 1
#define EE 131072         // B * 8192
#define NNODES 8192       // B * NPG
#define ROWS (BB * TT)    // 8208 CSR rows keyed by (g, sl=query)
#define ECAP 64           // entries per bucket; Poisson(16), P(>=64) ~ 3e-22
#define SP 544            // padded s extent (34 tiles of 16)
#define SSTR 548          // dense strip stride (floats); 548 mod 32 = 4

static constexpr size_t XROWS = (size_t)BB * TT;   // 8208 (= 513 * 16 exactly)
static constexpr size_t XSZ   = XROWS * CC;        // 1,050,624
static constexpr size_t VTSZ  = (size_t)BB * HH * DD * SP;  // 1,114,112

typedef unsigned short ushort_t;
typedef __attribute__((ext_vector_type(8))) short short8;
typedef __attribute__((ext_vector_type(4))) float floatx4;

__device__ __forceinline__ float gelu_exact(float v) {
    return 0.5f * v * (1.0f + erff(v * 0.70710678118654752440f));
}
__device__ __forceinline__ ushort_t f2bf(float f) {
    union { float f; unsigned u; } c; c.f = f;
    unsigned u = c.u;
    return (ushort_t)((u + 0x7FFFu + ((u >> 16) & 1u)) >> 16);   // RNE
}
// XOR-swizzled LDS offset (16B granules); stride in shorts, multiple of 8
__device__ __forceinline__ int swz(int row, int col, int stride) {
    int kb = col >> 3;
    return row * stride + (((kb ^ (row & 7)) << 3) | (col & 7));
}

// ---- QKV stage (8-wave, 512 thr): hs (swizzled 16x128 ln1 tile) -> qh, kh, vt ----
// qh/kh are per-head contiguous: [bh][t][16]. rowlim: valid local rows (16=pre, 8=mega).
__device__ __forceinline__ void qkv_stage8(const ushort_t* hs,
                                           const ushort_t* Wtq, const float* bq_,
                                           const ushort_t* Wtk, const float* bk_,
                                           const ushort_t* Wtv, const float* bv_,
                                           ushort_t* qh, ushort_t* kh, ushort_t* vt,
                                           int b, int t0, int wave, int lq, int quad,
                                           int rowlim) {
    const short* hsS = (const short*)hs;
    int c = wave * 16 + lq;
    const short* Ws[3] = {(const short*)Wtq, (const short*)Wtk, (const short*)Wtv};
    const float* bs[3] = {bq_, bk_, bv_};
    size_t rB = (size_t)c * CC;

    #pragma unroll
    for (int m = 0; m < 3; ++m) {
        const short* W = Ws[m];
        floatx4 a0 = {0.f,0.f,0.f,0.f};
        #pragma unroll
        for (int k0 = 0; k0 < CC; k0 += 32) {
            short8 af = *(const short8*)(hsS + swz(lq, k0 + quad * 8, 128));
            short8 b0 = *(const short8*)(W + rB + k0 + quad * 8);
            a0 = __builtin_amdgcn_mfma_f32_16x16x32_bf16(af, b0, a0, 0, 0, 0);
        }
        float bv0 = bs[m][c];
        #pragma unroll
        for (int rg = 0; rg < 4; ++rg) {
            int r8 = quad * 4 + rg;
            int t = t0 + r8;
            if (r8 >= rowlim || t >= TT) continue;   // pad row: discard
            float v0 = a0[rg] + bv0;
            size_t hr = ((size_t)(b * HH + wave) * TT + t) * DD + lq;  // head=wave, d=lq
            if (m == 0) {        // Q: fold 1/sqrt(D)=0.25 (exact)
                qh[hr] = f2bf(v0 * 0.25f);
            } else if (m == 1) { // K
                kh[hr] = f2bf(v0);
            } else {             // V, written transposed VT[bh][d][s]
                vt[((size_t)(b * HH + wave) * DD + lq) * SP + t] = f2bf(v0);
            }
        }
    }
}

// ---------------- merged: degree+CSR (blocks 0..511) | weight transpose (512..703) ----
__global__ __launch_bounds__(256) void deg_csr_tr_kernel(const int* __restrict__ ei,
                                                         const int* __restrict__ ea,
                                                         int* __restrict__ deg_in,
                                                         int* __restrict__ deg_out,
                                                         int* __restrict__ cnt,
                                                         int* __restrict__ ebuf,
                                                         const float* __restrict__ Wq,
                                                         const float* __restrict__ Wk,
                                                         const float* __restrict__ Wv,
                                                         const float* __restrict__ Wo,
                                                         const float* __restrict__ W1,
                                                         const float* __restrict__ W2,
                                                         ushort_t* __restrict__ wtqkvo,
                                                         ushort_t* __restrict__ wt1,
                                                         ushort_t* __restrict__ wt2) {
    int bid = blockIdx.x;
    int tid = threadIdx.x;
    if (bid < 512) {
        int e = bid * 256 + tid;
        int src = ei[e], dst = ei[EE + e];
        atomicAdd(&deg_out[src], 1);
        atomicAdd(&deg_in[dst], 1);
        int g = src >> 9;
        int sl = src - (g << 9) + 1;
        int dl = dst - (g << 9) + 1;
        int a = ea[e];
        a = (a < 0) ? 0 : (a > 9 ? 9 : a);
        a += 1;
        int row = g * TT + sl;
        int pos = atomicAdd(&cnt[row], 1);
        if (pos < ECAP) ebuf[(size_t)row * ECAP + pos] = dl | (a << 16);
        return;
    }
    // transpose tile z in [0,192): slot layout k*4+l (Q:0-3 K:4-7 V:8-11 O:12-15)
    int z = bid - 512;
    const float* src; ushort_t* dst; int K, N, tile;
    if (z < 64) {
        int zz = z >> 2; tile = z & 3;
        int k = zz >> 2, l = zz & 3;
        const float* s4[4] = {Wq, Wk, Wv, Wo};
        src = s4[k] + (size_t)l * CC * CC;
        dst = wtqkvo + (size_t)(k * 4 + l) * 16384;
        K = CC; N = CC;
    } else if (z < 128) {
        int l = (z - 64) >> 4; tile = (z - 64) & 15;
        src = W1 + (size_t)l * CC * FFN;
        dst = wt1 + (size_t)l * 65536;
        K = CC; N = FFN;
    } else {
        int l = (z - 128) >> 4; tile = (z - 128) & 15;
        src = W2 + (size_t)l * FFN * CC;
        dst = wt2 + (size_t)l * 65536;
        K = FFN; N = CC;
    }
    int tilesN = N >> 6;
    int k0 = (tile / tilesN) << 6;
    int n0 = (tile - (tile / tilesN) * tilesN) << 6;
    __shared__ float t[64][65];
    int c = tid & 63, rb = tid >> 6;
    #pragma unroll
    for (int kk = 0; kk < 64; kk += 4)
        t[kk + rb][c] = src[(size_t)(k0 + kk + rb) * N + n0 + c];
    __syncthreads();
    #pragma unroll
    for (int nn = 0; nn < 64; nn += 4)
        dst[(size_t)(n0 + nn + rb) * K + k0 + c] = f2bf(t[c][nn + rb]);
}

// ---------------- encode + ln1(L0) + QKV(L0): per-graph 16-row tiles, 512 thr ----
__global__ __launch_bounds__(512) void pre_kernel(const float* __restrict__ nf,
                                                  const float* __restrict__ Wn,
                                                  const float* __restrict__ bn,
                                                  const float* __restrict__ gt,
                                                  const float* __restrict__ ide,
                                                  const float* __restrict__ ode,
                                                  const int* __restrict__ deg_in,
                                                  const int* __restrict__ deg_out,
                                                  const float* __restrict__ ln1g_,
                                                  const float* __restrict__ ln1b_,
                                                  const ushort_t* __restrict__ wtqkvo,
                                                  const float* __restrict__ bq_,
                                                  const float* __restrict__ bk_,
                                                  const float* __restrict__ bv_,
                                                  float* __restrict__ x_,
                                                  ushort_t* __restrict__ qh,
                                                  ushort_t* __restrict__ kh,
                                                  ushort_t* __restrict__ vt) {
    int bid = blockIdx.x;
    int tid = threadIdx.x;
    int b = bid / 33, qt = bid - b * 33;
    int t0 = qt * 16;
    int wave = tid >> 6, lane = tid & 63, lq = lane & 15, quad = lane >> 4;

    __shared__ ushort_t hs[16 * 128];
    __shared__ float sred[8][16][2];

    int c = wave * 16 + lq;
    float w0[4];
    #pragma unroll
    for (int rg = 0; rg < 4; ++rg) {
        int t = t0 + quad * 4 + rg;
        int tc = min(t, TT - 1);            // clamp pad rows for reads
        float v0;
        if (tc == 0) {
            v0 = gt[c];
        } else {
            int i = b * NPG + tc - 1;
            float f0 = nf[i*3+0], f1 = nf[i*3+1], f2 = nf[i*3+2];
            v0 = bn[c] + f0*Wn[0*CC + c] + f1*Wn[1*CC + c] + f2*Wn[2*CC + c];
            int di = min(deg_in[i], 511);
            int dq = min(deg_out[i], 511);
            v0 += ide[(size_t)di * CC + c] + ode[(size_t)dq * CC + c];
        }
        if (t < TT) x_[((size_t)b * TT + t) * CC + c] = v0;
        w0[rg] = v0;
    }
    #pragma unroll
    for (int rg = 0; rg < 4; ++rg) {
        float s1 = w0[rg];
        float s2 = w0[rg] * w0[rg];
        #pragma unroll
        for (int m = 1; m < 16; m <<= 1) {
            s1 += __shfl_xor(s1, m, 64);
            s2 += __shfl_xor(s2, m, 64);
        }
        if (lq == 0) { sred[wave][quad*4+rg][0] = s1; sred[wave][quad*4+rg][1] = s2; }
    }
    __syncthreads();
    float g0 = ln1g_[c], lb0 = ln1b_[c];
    #pragma unroll
    for (int rg = 0; rg < 4; ++rg) {
        int row = quad * 4 + rg;
        float S1 = 0.f, S2 = 0.f;
        #pragma unroll
        for (int w = 0; w < 8; ++w) { S1 += sred[w][row][0]; S2 += sred[w][row][1]; }
        float mn = S1 * (1.0f/CC);
        float var = S2 * (1.0f/CC) - mn * mn;
        float rs = rsqrtf(var + 1e-5f);
        hs[swz(row, c, 128)] = f2bf((w0[rg] - mn) * rs * g0 + lb0);
    }
    __syncthreads();
    qkv_stage8(hs, wtqkvo, bq_,
               wtqkvo + (size_t)4 * 16384, bk_,
               wtqkvo + (size_t)8 * 16384, bv_,
               qh, kh, vt, b, t0, wave, lq, quad, 16);
}

// ---------------- attention kernel: one block per (qt, b*h), 4 waves ----------------
//  dense single-head bias strip [16][548] f32 built ONCE per block, then fence-free
//  s-loop; Q/K fragments are per-head CONTIGUOUS (512B/fragment) loads from qh/kh.
__global__ __launch_bounds__(256, 4) void attn_kernel(const ushort_t* __restrict__ qhr,
                                                      const ushort_t* __restrict__ khr,
                                                      const ushort_t* __restrict__ vtr,
                                                      const int* __restrict__ cnt,
                                                      const int* __restrict__ ebuf,
                                                      const float* __restrict__ ebt,
                                                      const float* __restrict__ vnode,
                                                      ushort_t* __restrict__ obf) {
    int qt = blockIdx.x;
    int bh = blockIdx.y;
    int b = bh >> 3, h = bh & (HH - 1);
    int tid = threadIdx.x;
    int wave = tid >> 6, lane = tid & 63, lq = lane & 15, quad = lane >> 4;

    __shared__ __align__(16) float strip[16 * SSTR];   // 35072 B; epilogue aliases it
    __shared__ __align__(16) int elist[16 * 64];       // 4096 B
    __shared__ float ebtl[12];
    __shared__ int cn_s[16];

    // ---- build: zero strip, stage CSR rows, per-head edge-bias table ----
    for (int i = tid; i < 16 * SSTR / 4; i += 256)
        ((float4*)strip)[i] = make_float4(0.f, 0.f, 0.f, 0.f);
    if (tid < 11) ebtl[tid] = ebt[tid * 8 + h];
    {
        int r = tid >> 4, j4 = (tid & 15) * 4;
        int qrow = qt * 16 + r;
        bool rv = (qrow >= 1) && (qrow < TT);
        size_t crow = (size_t)b * TT + (rv ? qrow : 0);
        *(int4*)&elist[r * 64 + j4] = *(const int4*)(ebuf + crow * ECAP + j4);
        if ((tid & 15) == 0) cn_s[r] = rv ? min(cnt[crow], ECAP) : 0;
    }
    __syncthreads();
    if (tid < 16) {                         // vnode column s==0 (valid q>0 rows only)
        int qrow = qt * 16 + tid;
        if (qrow >= 1 && qrow < TT) strip[tid * SSTR] = vnode[h];
    }
    {
        int r = tid >> 4;
        int cn = cn_s[r];
        for (int j = tid & 15; j < cn; j += 16) {
            int e = elist[r * 64 + j];
            atomicAdd(&strip[r * SSTR + (e & 0xFFFF)], ebtl[e >> 16]);
        }
    }
    __syncthreads();

    // ---- s-loop: wave w handles sp = w, w+4, ... (<17); 1-deep prefetch ----
    int qg = qt * 16 + lq;
    int qr = min(qg, TT - 1);
    short8 z8 = {0,0,0,0,0,0,0,0};
    const short* qhS = (const short*)qhr;
    const short* khS = (const short*)khr;
    short8 qf = z8;
    if (quad < 2)
        qf = *(const short8*)(qhS + ((size_t)bh * TT + qr) * DD + quad * 8);
    const short* vtS = (const short*)(vtr + (size_t)bh * DD * SP);

    floatx4 oacc = {0.f, 0.f, 0.f, 0.f};
    float lsum = 0.f;

    short8 af0c = z8, af1c = z8, vfc;
    {
        int sp = wave;
        int t0r = min(sp * 2 * 16 + lq, TT - 1);
        int t1r = min((sp * 2 + 1) * 16 + lq, TT - 1);
        if (quad < 2) {
            af0c = *(const short8*)(khS + ((size_t)bh * TT + t0r) * DD + quad * 8);
            af1c = *(const short8*)(khS + ((size_t)bh * TT + t1r) * DD + quad * 8);
        }
        vfc = *(const short8*)(vtS + (size_t)lq * SP + sp * 32 + quad * 8);
    }

    for (int sp = wave; sp < 17; sp += 4) {
        int spn = sp + 4;
        short8 af0n = z8, af1n = z8, vfn = z8;
        if (spn < 17) {
            int t0r = min(spn * 2 * 16 + lq, TT - 1);
            int t1r = min((spn * 2 + 1) * 16 + lq, TT - 1);
            if (quad < 2) {
                af0n = *(const short8*)(khS + ((size_t)bh * TT + t0r) * DD + quad * 8);
                af1n = *(const short8*)(khS + ((size_t)bh * TT + t1r) * DD + quad * 8);
            }
            vfn = *(const short8*)(vtS + (size_t)lq * SP + spn * 32 + quad * 8);
        }

        int roff = lq * SSTR + sp * 32 + quad * 4;
        float4 bia = *(const float4*)&strip[roff];
        float4 bib = *(const float4*)&strip[roff + 16];

        unsigned pw[2][2];
        #pragma unroll
        for (int t = 0; t < 2; ++t) {
            int st = sp * 2 + t;
            floatx4 cc4 = __builtin_amdgcn_mfma_f32_16x16x32_bf16(
                t ? af1c : af0c, qf, (floatx4){0.f, 0.f, 0.f, 0.f}, 0, 0, 0);
            float4 bi = t ? bib : bia;
            float biv[4] = {bi.x, bi.y, bi.z, bi.w};
            float pr[4];
            #pragma unroll
            for (int rg = 0; rg < 4; ++rg) {
                int s = st * 16 + quad * 4 + rg;
                float p = 0.f;
                if (s < TT) p = __expf(cc4[rg] + biv[rg]);
                lsum += p;
                pr[rg] = p;
            }
            pw[t][0] = (unsigned)f2bf(pr[0]) | ((unsigned)f2bf(pr[1]) << 16);
            pw[t][1] = (unsigned)f2bf(pr[2]) | ((unsigned)f2bf(pr[3]) << 16);
        }
        int srcA = lq + (((2 * quad) & 3) << 4);
        int srcB = lq + (((2 * quad + 1) & 3) << 4);
        int a00 = __shfl((int)pw[0][0], srcA, 64);
        int a01 = __shfl((int)pw[0][1], srcA, 64);
        int a10 = __shfl((int)pw[1][0], srcA, 64);
        int a11 = __shfl((int)pw[1][1], srcA, 64);
        int b00 = __shfl((int)pw[0][0], srcB, 64);
        int b01 = __shfl((int)pw[0][1], srcB, 64);
        int b10 = __shfl((int)pw[1][0], srcB, 64);
        int b11 = __shfl((int)pw[1][1], srcB, 64);
        union { int u[4]; short8 s8; } pu;
        bool lo = quad < 2;
        pu.u[0] = lo ? a00 : a10;
        pu.u[1] = lo ? a01 : a11;
        pu.u[2] = lo ? b00 : b10;
        pu.u[3] = lo ? b01 : b11;
        oacc = __builtin_amdgcn_mfma_f32_16x16x32_bf16(vfc, pu.s8, oacc, 0, 0, 0);

        af0c = af0n; af1c = af1n; vfc = vfn;
    }

    // ---- cross-wave reduce (4 waves) -> obf ----
    lsum += __shfl_xor(lsum, 16, 64);
    lsum += __shfl_xor(lsum, 32, 64);
    __syncthreads();                       // all strip reads done; reuse as arena
    float* redw = strip;
    float* lsumS = strip + 1088;
    #pragma unroll
    for (int rg = 0; rg < 4; ++rg)
        redw[wave * 272 + (quad * 4 + rg) * 17 + lq] = oacc[rg];
    if (quad == 0) lsumS[wave * 16 + lq] = lsum;
    __syncthreads();
    {
        int q = tid >> 4, d = tid & 15;
        float o = 0.f, L = 0.f;
        #pragma unroll
        for (int w = 0; w < 4; ++w) {
            o += redw[w * 272 + d * 17 + q];
            L += lsumS[w * 16 + q];
        }
        int qq = qt * 16 + q;
        if (qq < TT)
            obf[((size_t)(b * TT + qq)) * CC + h * DD + d] = f2bf(o / L);
    }
}

// ---------------- mega kernel (8 waves, 8-ROW tiles, 1040 blocks): o-proj+res+ln2+
//   ffn1+gelu+ffn2+res + (ln1next + QKVnext) or folded head on the last layer.
//   MFMA frames stay 16-row; local rows 8-15 are pad (clamped reads, guarded stores).
__global__ __launch_bounds__(512, 8) void mega_kernel(const ushort_t* __restrict__ obf,
                                                      const ushort_t* __restrict__ WtO,
                                                      const float* __restrict__ bo_,
                                                      const float* __restrict__ ln2g_,
                                                      const float* __restrict__ ln2b_,
                                                      const ushort_t* __restrict__ Wt1_,
                                                      const float* __restrict__ b1_,
                                                      const ushort_t* __restrict__ Wt2_,
                                                      const float* __restrict__ b2_,
                                                      const float* __restrict__ ln1g_,
                                                      const float* __restrict__ ln1b_,
                                                      const ushort_t* __restrict__ Wtq,
                                                      const float* __restrict__ bq_,
                                                      const ushort_t* __restrict__ Wtk,
                                                      const float* __restrict__ bk_,
                                                      const ushort_t* __restrict__ Wtv,
                                                      const float* __restrict__ bv_,
                                                      const float* __restrict__ nfg,
                                                      const float* __restrict__ nfb,
                                                      const float* __restrict__ Wc1,
                                                      const float* __restrict__ bc1,
                                                      const float* __restrict__ Wc2,
                                                      const float* __restrict__ bc2,
                                                      float* __restrict__ x_,
                                                      ushort_t* __restrict__ qhw,
                                                      ushort_t* __restrict__ khw,
                                                      ushort_t* __restrict__ vtw,
                                                      float* __restrict__ out,
                                                      int doQKV) {
    int qt = blockIdx.x, b = blockIdx.y;
    int tid = threadIdx.x;
    int wave = tid >> 6, lane = tid & 63, lq = lane & 15, quad = lane >> 4;

    __shared__ __align__(16) ushort_t hs[16 * 128];
    __shared__ __align__(16) ushort_t ms[16 * 512];
    __shared__ float sred[8][16][2];

    int t0 = qt * 8;                       // 8-row tile; rows 8-15 of frame are pad
    int c = wave * 16 + lq;
    float vv0[4];

    // ---- entry prefetch: x residuals (owned rows exact; pad rows race-tolerant) ----
    float xr[4];
    #pragma unroll
    for (int rg = 0; rg < 4; ++rg) {
        int t = t0 + quad * 4 + rg;
        xr[rg] = x_[((size_t)b * TT + min(t, TT - 1)) * CC + c];
    }

    // ---- stage 1: o-proj (16x16 frame per wave, K=128, A rows from global obf) + res + ln2 -> hs
    {
        const short* obS = (const short*)obf;
        size_t arow = (size_t)b * TT + min(t0 + lq, TT - 1);
        const short* W = (const short*)WtO;
        size_t rB = (size_t)c * CC;
        floatx4 a0 = {0.f,0.f,0.f,0.f};
        #pragma unroll
        for (int k0 = 0; k0 < CC; k0 += 32) {
            short8 af = *(const short8*)(obS + arow * CC + k0 + quad * 8);
            short8 b0 = *(const short8*)(W + rB + k0 + quad * 8);
            a0 = __builtin_amdgcn_mfma_f32_16x16x32_bf16(af, b0, a0, 0, 0, 0);
        }
        float bv0 = bo_[c];
        #pragma unroll
        for (int rg = 0; rg < 4; ++rg)
            vv0[rg] = a0[rg] + bv0 + xr[rg];
        #pragma unroll
        for (int rg = 0; rg < 4; ++rg) {
            float s1 = vv0[rg];
            float s2 = vv0[rg] * vv0[rg];
            #pragma unroll
            for (int m = 1; m < 16; m <<= 1) {
                s1 += __shfl_xor(s1, m, 64);
                s2 += __shfl_xor(s2, m, 64);
            }
            if (lq == 0) { sred[wave][quad*4+rg][0] = s1; sred[wave][quad*4+rg][1] = s2; }
        }
        __syncthreads();
        float g0 = ln2g_[c], lb0 = ln2b_[c];
        #pragma unroll
        for (int rg = 0; rg < 4; ++rg) {
            int row = quad * 4 + rg;
            float S1 = 0.f, S2 = 0.f;
            #pragma unroll
            for (int w = 0; w < 8; ++w) { S1 += sred[w][row][0]; S2 += sred[w][row][1]; }
            float mn = S1 * (1.0f/CC);
            float var = S2 * (1.0f/CC) - mn * mn;
            float rs = rsqrtf(var + 1e-5f);
            hs[swz(row, c, 128)] = f2bf((vv0[rg] - mn) * rs * g0 + lb0);
        }
    }
    __syncthreads();

    // ---- stage 2: ffn1 (wave covers mid cols wave*64..+63, K=128) + gelu -> ms ----
    {
        const short* hsS = (const short*)hs;
        const short* W = (const short*)Wt1_;
        #pragma unroll
        for (int nt = 0; nt < 4; ++nt) {
            int n = wave * 64 + nt * 16;
            size_t rB = (size_t)(n + lq) * CC;
            floatx4 a0 = {0.f,0.f,0.f,0.f};
            #pragma unroll
            for (int k0 = 0; k0 < CC; k0 += 32) {
                short8 af = *(const short8*)(hsS + swz(lq, k0 + quad * 8, 128));
                short8 b0 = *(const short8*)(W + rB + k0 + quad * 8);
                a0 = __builtin_amdgcn_mfma_f32_16x16x32_bf16(af, b0, a0, 0, 0, 0);
            }
            float bb0 = b1_[n + lq];
            #pragma unroll
            for (int rg = 0; rg < 4; ++rg)
                ms[swz(quad * 4 + rg, n + lq, 512)] = f2bf(gelu_exact(a0[rg] + bb0));
        }
    }
    __syncthreads();

    // ---- stage 3: ffn2 (16x16 frame per wave, K=512 from ms) + res ----
    float w0[4];
    {
        const short* msS = (const short*)ms;
        const short* W = (const short*)Wt2_;
        size_t rB = (size_t)c * FFN;
        floatx4 a0 = {0.f,0.f,0.f,0.f};
        #pragma unroll 8
        for (int k0 = 0; k0 < FFN; k0 += 32) {
            short8 af = *(const short8*)(msS + swz(lq, k0 + quad * 8, 512));
            short8 b0 = *(const short8*)(W + rB + k0 + quad * 8);
            a0 = __builtin_amdgcn_mfma_f32_16x16x32_bf16(af, b0, a0, 0, 0, 0);
        }
        float bv0 = b2_[c];
        #pragma unroll
        for (int rg = 0; rg < 4; ++rg) {
            int r8 = quad * 4 + rg;
            int t = t0 + r8;
            w0[rg] = a0[rg] + bv0 + vv0[rg];
            if (r8 < 8 && t < TT) x_[((size_t)b * TT + t) * CC + c] = w0[rg];
        }
    }

    if (doQKV) {
        // ln1(next layer) -> hs, then QKV into ping-pong buffers
        #pragma unroll
        for (int rg = 0; rg < 4; ++rg) {
            float s1 = w0[rg];
            float s2 = w0[rg] * w0[rg];
            #pragma unroll
            for (int m = 1; m < 16; m <<= 1) {
                s1 += __shfl_xor(s1, m, 64);
                s2 += __shfl_xor(s2, m, 64);
            }
            if (lq == 0) { sred[wave][quad*4+rg][0] = s1; sred[wave][quad*4+rg][1] = s2; }
        }
        __syncthreads();
        float g0 = ln1g_[c], lb0 = ln1b_[c];
        #pragma unroll
        for (int rg = 0; rg < 4; ++rg) {
            int row = quad * 4 + rg;
            float S1 = 0.f, S2 = 0.f;
            #pragma unroll
            for (int w = 0; w < 8; ++w) { S1 += sred[w][row][0]; S2 += sred[w][row][1]; }
            float mn = S1 * (1.0f/CC);
            float var = S2 * (1.0f/CC) - mn * mn;
            float rs = rsqrtf(var + 1e-5f);
            hs[swz(row, c, 128)] = f2bf((w0[rg] - mn) * rs * g0 + lb0);
        }
        __syncthreads();
        qkv_stage8(hs, Wtq, bq_, Wtk, bk_, Wtv, bv_, qhw, khw, vtw, b, t0, wave, lq, quad, 8);
        return;
    }

    // ---- last layer: folded head for the graph-token row (tile qt == 0, row 0) ----
    if (qt != 0) return;

    __syncthreads();                      // all waves done reading ms; reuse as scratch
    float* hrow = (float*)ms;             // 128
    float* xfs  = hrow + CC;              // 128
    float* c1s  = xfs + CC;               // 64
    float* red  = c1s + 64;               // 4
    if (quad == 0) hrow[c] = w0[0];       // row 0 of tile: quad*4+rg == 0
    __syncthreads();

    {
        int ct = tid;
        float v = 0.f, s1 = 0.f, s2 = 0.f;
        if (ct < CC) { v = hrow[ct]; s1 = v; s2 = v * v; }
        #pragma unroll
        for (int m = 32; m >= 1; m >>= 1) {
            s1 += __shfl_xor(s1, m, 64);
            s2 += __shfl_xor(s2, m, 64);
        }
        int w = ct >> 6;
        if (ct < CC && (ct & 63) == 0) { red[w*2] = s1; red[w*2+1] = s2; }
        __syncthreads();
        if (ct < CC) {
            float S1 = red[0] + red[2], S2 = red[1] + red[3];
            float mn = S1 * (1.0f/CC);
            float var = S2 * (1.0f/CC) - mn * mn;
            float rs = rsqrtf(var + 1e-5f);
            xfs[ct] = (v - mn) * rs * nfg[ct] + nfb[ct];
        }
        __syncthreads();
        if (ct < 64) {
            float acc = bc1[ct];
            #pragma unroll 4
            for (int k = 0; k < CC; ++k) acc = fmaf(xfs[k], Wc1[(size_t)k * 64 + ct], acc);
            c1s[ct] = gelu_exact(acc);
        }
        __syncthreads();
        if (ct < NCLS) {
            float acc = bc2[ct];
            #pragma unroll 4
            for (int j = 0; j < 64; ++j) acc = fmaf(c1s[j], Wc2[(size_t)j * NCLS + ct], acc);
            out[(size_t)b * NCLS + ct] = acc;
        }
    }
}

extern "C" void kernel_launch(void* const* d_in, const int* in_sizes, int n_in,
                              void* d_out, int out_size, void* d_ws, size_t ws_size,
                              hipStream_t stream) {
    const float* node_feats = (const float*)d_in[0];
    const int*   edge_index = (const int*)d_in[1];
    const int*   edge_attr  = (const int*)d_in[2];
    const float* W_node  = (const float*)d_in[4];
    const float* b_node  = (const float*)d_in[5];
    const float* g_token = (const float*)d_in[6];
    const float* ebt     = (const float*)d_in[7];
    const float* ide     = (const float*)d_in[8];
    const float* ode     = (const float*)d_in[9];
    const float* vnode   = (const float*)d_in[10];
    const float* Wq = (const float*)d_in[11];
    const float* bq = (const float*)d_in[12];
    const float* Wk = (const float*)d_in[13];
    const float* bk = (const float*)d_in[14];
    const float* Wv = (const float*)d_in[15];
    const float* bv = (const float*)d_in[16];
    const float* Wo = (const float*)d_in[17];
    const float* bo = (const float*)d_in[18];
    const float* ln1g = (const float*)d_in[19];
    const float* ln1b = (const float*)d_in[20];
    const float* ln2g = (const float*)d_in[21];
    const float* ln2b = (const float*)d_in[22];
    const float* W1 = (const float*)d_in[23];
    const float* b1 = (const float*)d_in[24];
    const float* W2 = (const float*)d_in[25];
    const float* b2 = (const float*)d_in[26];
    const float* nfg = (const float*)d_in[27];
    const float* nfb = (const float*)d_in[28];
    const float* Wc1 = (const float*)d_in[29];
    const float* bc1 = (const float*)d_in[30];
    const float* Wc2 = (const float*)d_in[31];
    const float* bc2 = (const float*)d_in[32];
    float* out = (float*)d_out;

    // ---- workspace (all chunks 16B-aligned); qh/kh/vt double-buffered ----
    char* base = (char*)d_ws;
    float* x      = (float*)base;     base += XSZ * 4;
    ushort_t* qh0 = (ushort_t*)base;  base += XSZ * 2;
    ushort_t* kh0 = (ushort_t*)base;  base += XSZ * 2;
    ushort_t* vt0 = (ushort_t*)base;  base += VTSZ * 2;
    ushort_t* qh1 = (ushort_t*)base;  base += XSZ * 2;
    ushort_t* kh1 = (ushort_t*)base;  base += XSZ * 2;
    ushort_t* vt1 = (ushort_t*)base;  base += VTSZ * 2;
    ushort_t* obf = (ushort_t*)base;  base += XSZ * 2;
    ushort_t* wtqkvo = (ushort_t*)base; base += (size_t)16 * 16384 * 2;
    ushort_t* wt1 = (ushort_t*)base;  base += (size_t)4 * 65536 * 2;
    ushort_t* wt2 = (ushort_t*)base;  base += (size_t)4 * 65536 * 2;
    int* deg_in  = (int*)base;        base += NNODES * 4;
    int* deg_out = (int*)base;        base += NNODES * 4;
    int* cnt     = (int*)base;        base += (size_t)ROWS * 4;
    int* ebuf    = (int*)base;        base += (size_t)ROWS * ECAP * 4;

    ushort_t* qhs[2] = {qh0, qh1};
    ushort_t* khs[2] = {kh0, kh1};
    ushort_t* vts[2] = {vt0, vt1};

    hipMemsetAsync(deg_in, 0, (size_t)(2 * NNODES + ROWS) * 4, stream);
    deg_csr_tr_kernel<<<512 + 192, 256, 0, stream>>>(
        edge_index, edge_attr, deg_in, deg_out, cnt, ebuf,
        Wq, Wk, Wv, Wo, W1, W2, wtqkvo, wt1, wt2);

    pre_kernel<<<528, 512, 0, stream>>>(
        node_feats, W_node, b_node, g_token, ide, ode, deg_in, deg_out,
        ln1g, ln1b, wtqkvo, bq, bk, bv, x, qh0, kh0, vt0);

    for (int l = 0; l < LL; ++l) {
        int rd = l & 1, wr = rd ^ 1;
        int ln = (l + 1) % LL;   // next layer (unused when l==LL-1)

        attn_kernel<<<dim3(33, BB * HH), 256, 0, stream>>>(
            qhs[rd], khs[rd], vts[rd], cnt, ebuf, ebt, vnode, obf);

        mega_kernel<<<dim3(65, BB), 512, 0, stream>>>(
            obf,
            wtqkvo + (size_t)(12 + l)*16384, bo + l*CC,
            ln2g + l*CC, ln2b + l*CC,
            wt1 + (size_t)l*65536, b1 + l*FFN,
            wt2 + (size_t)l*65536, b2 + l*CC,
            ln1g + ln*CC, ln1b + ln*CC,
            wtqkvo + (size_t)(0 + ln)*16384, bq + ln*CC,
            wtqkvo + (size_t)(4 + ln)*16384, bk + ln*CC,
            wtqkvo + (size_t)(8 + ln)*16384, bv + ln*CC,
            nfg, nfb, Wc1, bc1, Wc2, bc2,
            x, qhs[wr], khs[wr], vts[wr], out,
            (l < LL-1) ? 1 : 0);
    }
}

// Round 8
// 537.152 us; speedup vs baseline: 1.0487x; 1.0487x over previous
//
#include <hip/hip_runtime.h>
#include <hip/hip_bf16.h>

#define BB 16
#define NPG 512
#define CC 128
#define HH 8
#define LL 4
#define FFN 512
#define NCLS 4
#define DD 16
#define TT 513            // NPG + 1
#define EE 131072         // B * 8192
#define NNODES 8192       // B * NPG
#define ROWS (BB * TT)    // 8208 CSR rows keyed by (g, sl=query)
#define ECAP 64           // entries per bucket; Poisson(16), P(>=64) ~ 3e-22
#define SP 544            // padded s extent (34 tiles of 16)
#define SSTR 548          // dense strip stride (floats); 548 mod 32 = 4

static constexpr size_t XROWS = (size_t)BB * TT;   // 8208 (= 513 * 16 exactly)
static constexpr size_t XSZ   = XROWS * CC;        // 1,050,624
static constexpr size_t VTSZ  = (size_t)BB * HH * DD * SP;  // 1,114,112

typedef unsigned short ushort_t;
typedef __attribute__((ext_vector_type(8))) short short8;
typedef __attribute__((ext_vector_type(4))) float floatx4;

__device__ __forceinline__ float gelu_exact(float v) {
    return 0.5f * v * (1.0f + erff(v * 0.70710678118654752440f));
}
__device__ __forceinline__ ushort_t f2bf(float f) {
    union { float f; unsigned u; } c; c.f = f;
    unsigned u = c.u;
    return (ushort_t)((u + 0x7FFFu + ((u >> 16) & 1u)) >> 16);   // RNE
}
// XOR-swizzled LDS offset (16B granules); stride in shorts, multiple of 8
__device__ __forceinline__ int swz(int row, int col, int stride) {
    int kb = col >> 3;
    return row * stride + (((kb ^ (row & 7)) << 3) | (col & 7));
}

// ---- QKV stage (8-wave, 512 thr): hs (swizzled 16x128 ln1 tile) -> qh, kh, vt ----
// qh/kh are per-head contiguous: [bh][t][16]. rowlim: valid local rows (16=pre, 8=mega).
__device__ __forceinline__ void qkv_stage8(const ushort_t* hs,
                                           const ushort_t* Wtq, const float* bq_,
                                           const ushort_t* Wtk, const float* bk_,
                                           const ushort_t* Wtv, const float* bv_,
                                           ushort_t* qh, ushort_t* kh, ushort_t* vt,
                                           int b, int t0, int wave, int lq, int quad,
                                           int rowlim) {
    const short* hsS = (const short*)hs;
    int c = wave * 16 + lq;
    const short* Ws[3] = {(const short*)Wtq, (const short*)Wtk, (const short*)Wtv};
    const float* bs[3] = {bq_, bk_, bv_};
    size_t rB = (size_t)c * CC;

    #pragma unroll
    for (int m = 0; m < 3; ++m) {
        const short* W = Ws[m];
        floatx4 a0 = {0.f,0.f,0.f,0.f};
        #pragma unroll
        for (int k0 = 0; k0 < CC; k0 += 32) {
            short8 af = *(const short8*)(hsS + swz(lq, k0 + quad * 8, 128));
            short8 b0 = *(const short8*)(W + rB + k0 + quad * 8);
            a0 = __builtin_amdgcn_mfma_f32_16x16x32_bf16(af, b0, a0, 0, 0, 0);
        }
        float bv0 = bs[m][c];
        #pragma unroll
        for (int rg = 0; rg < 4; ++rg) {
            int r8 = quad * 4 + rg;
            int t = t0 + r8;
            if (r8 >= rowlim || t >= TT) continue;   // pad row: discard
            float v0 = a0[rg] + bv0;
            size_t hr = ((size_t)(b * HH + wave) * TT + t) * DD + lq;  // head=wave, d=lq
            if (m == 0) {        // Q: fold 1/sqrt(D)=0.25 (exact)
                qh[hr] = f2bf(v0 * 0.25f);
            } else if (m == 1) { // K
                kh[hr] = f2bf(v0);
            } else {             // V, written transposed VT[bh][d][s]
                vt[((size_t)(b * HH + wave) * DD + lq) * SP + t] = f2bf(v0);
            }
        }
    }
}

// ---------------- merged: degree+CSR (blocks 0..511) | weight transpose (512..703) ----
__global__ __launch_bounds__(256) void deg_csr_tr_kernel(const int* __restrict__ ei,
                                                         const int* __restrict__ ea,
                                                         int* __restrict__ deg_in,
                                                         int* __restrict__ deg_out,
                                                         int* __restrict__ cnt,
                                                         int* __restrict__ ebuf,
                                                         const float* __restrict__ Wq,
                                                         const float* __restrict__ Wk,
                                                         const float* __restrict__ Wv,
                                                         const float* __restrict__ Wo,
                                                         const float* __restrict__ W1,
                                                         const float* __restrict__ W2,
                                                         ushort_t* __restrict__ wtqkvo,
                                                         ushort_t* __restrict__ wt1,
                                                         ushort_t* __restrict__ wt2) {
    int bid = blockIdx.x;
    int tid = threadIdx.x;
    if (bid < 512) {
        int e = bid * 256 + tid;
        int src = ei[e], dst = ei[EE + e];
        atomicAdd(&deg_out[src], 1);
        atomicAdd(&deg_in[dst], 1);
        int g = src >> 9;
        int sl = src - (g << 9) + 1;
        int dl = dst - (g << 9) + 1;
        int a = ea[e];
        a = (a < 0) ? 0 : (a > 9 ? 9 : a);
        a += 1;
        int row = g * TT + sl;
        int pos = atomicAdd(&cnt[row], 1);
        if (pos < ECAP) ebuf[(size_t)row * ECAP + pos] = dl | (a << 16);
        return;
    }
    // transpose tile z in [0,192): slot layout k*4+l (Q:0-3 K:4-7 V:8-11 O:12-15)
    int z = bid - 512;
    const float* src; ushort_t* dst; int K, N, tile;
    if (z < 64) {
        int zz = z >> 2; tile = z & 3;
        int k = zz >> 2, l = zz & 3;
        const float* s4[4] = {Wq, Wk, Wv, Wo};
        src = s4[k] + (size_t)l * CC * CC;
        dst = wtqkvo + (size_t)(k * 4 + l) * 16384;
        K = CC; N = CC;
    } else if (z < 128) {
        int l = (z - 64) >> 4; tile = (z - 64) & 15;
        src = W1 + (size_t)l * CC * FFN;
        dst = wt1 + (size_t)l * 65536;
        K = CC; N = FFN;
    } else {
        int l = (z - 128) >> 4; tile = (z - 128) & 15;
        src = W2 + (size_t)l * FFN * CC;
        dst = wt2 + (size_t)l * 65536;
        K = FFN; N = CC;
    }
    int tilesN = N >> 6;
    int k0 = (tile / tilesN) << 6;
    int n0 = (tile - (tile / tilesN) * tilesN) << 6;
    __shared__ float t[64][65];
    int c = tid & 63, rb = tid >> 6;
    #pragma unroll
    for (int kk = 0; kk < 64; kk += 4)
        t[kk + rb][c] = src[(size_t)(k0 + kk + rb) * N + n0 + c];
    __syncthreads();
    #pragma unroll
    for (int nn = 0; nn < 64; nn += 4)
        dst[(size_t)(n0 + nn + rb) * K + k0 + c] = f2bf(t[c][nn + rb]);
}

// ---------------- encode + ln1(L0) + QKV(L0): per-graph 16-row tiles, 512 thr ----
__global__ __launch_bounds__(512) void pre_kernel(const float* __restrict__ nf,
                                                  const float* __restrict__ Wn,
                                                  const float* __restrict__ bn,
                                                  const float* __restrict__ gt,
                                                  const float* __restrict__ ide,
                                                  const float* __restrict__ ode,
                                                  const int* __restrict__ deg_in,
                                                  const int* __restrict__ deg_out,
                                                  const float* __restrict__ ln1g_,
                                                  const float* __restrict__ ln1b_,
                                                  const ushort_t* __restrict__ wtqkvo,
                                                  const float* __restrict__ bq_,
                                                  const float* __restrict__ bk_,
                                                  const float* __restrict__ bv_,
                                                  float* __restrict__ x_,
                                                  ushort_t* __restrict__ qh,
                                                  ushort_t* __restrict__ kh,
                                                  ushort_t* __restrict__ vt) {
    int bid = blockIdx.x;
    int tid = threadIdx.x;
    int b = bid / 33, qt = bid - b * 33;
    int t0 = qt * 16;
    int wave = tid >> 6, lane = tid & 63, lq = lane & 15, quad = lane >> 4;

    __shared__ ushort_t hs[16 * 128];
    __shared__ float sred[8][16][2];

    int c = wave * 16 + lq;
    float w0[4];
    #pragma unroll
    for (int rg = 0; rg < 4; ++rg) {
        int t = t0 + quad * 4 + rg;
        int tc = min(t, TT - 1);            // clamp pad rows for reads
        float v0;
        if (tc == 0) {
            v0 = gt[c];
        } else {
            int i = b * NPG + tc - 1;
            float f0 = nf[i*3+0], f1 = nf[i*3+1], f2 = nf[i*3+2];
            v0 = bn[c] + f0*Wn[0*CC + c] + f1*Wn[1*CC + c] + f2*Wn[2*CC + c];
            int di = min(deg_in[i], 511);
            int dq = min(deg_out[i], 511);
            v0 += ide[(size_t)di * CC + c] + ode[(size_t)dq * CC + c];
        }
        if (t < TT) x_[((size_t)b * TT + t) * CC + c] = v0;
        w0[rg] = v0;
    }
    #pragma unroll
    for (int rg = 0; rg < 4; ++rg) {
        float s1 = w0[rg];
        float s2 = w0[rg] * w0[rg];
        #pragma unroll
        for (int m = 1; m < 16; m <<= 1) {
            s1 += __shfl_xor(s1, m, 64);
            s2 += __shfl_xor(s2, m, 64);
        }
        if (lq == 0) { sred[wave][quad*4+rg][0] = s1; sred[wave][quad*4+rg][1] = s2; }
    }
    __syncthreads();
    float g0 = ln1g_[c], lb0 = ln1b_[c];
    #pragma unroll
    for (int rg = 0; rg < 4; ++rg) {
        int row = quad * 4 + rg;
        float S1 = 0.f, S2 = 0.f;
        #pragma unroll
        for (int w = 0; w < 8; ++w) { S1 += sred[w][row][0]; S2 += sred[w][row][1]; }
        float mn = S1 * (1.0f/CC);
        float var = S2 * (1.0f/CC) - mn * mn;
        float rs = rsqrtf(var + 1e-5f);
        hs[swz(row, c, 128)] = f2bf((w0[rg] - mn) * rs * g0 + lb0);
    }
    __syncthreads();
    qkv_stage8(hs, wtqkvo, bq_,
               wtqkvo + (size_t)4 * 16384, bk_,
               wtqkvo + (size_t)8 * 16384, bv_,
               qh, kh, vt, b, t0, wave, lq, quad, 16);
}

// ---------------- attention kernel: one block per (qt, b*h), 4 waves ----------------
//  dense single-head bias strip [16][548] f32 built ONCE per block, then fence-free
//  s-loop; Q/K fragments are per-head CONTIGUOUS (512B/fragment) loads from qh/kh.
__global__ __launch_bounds__(256, 4) void attn_kernel(const ushort_t* __restrict__ qhr,
                                                      const ushort_t* __restrict__ khr,
                                                      const ushort_t* __restrict__ vtr,
                                                      const int* __restrict__ cnt,
                                                      const int* __restrict__ ebuf,
                                                      const float* __restrict__ ebt,
                                                      const float* __restrict__ vnode,
                                                      ushort_t* __restrict__ obf) {
    int qt = blockIdx.x;
    int bh = blockIdx.y;
    int b = bh >> 3, h = bh & (HH - 1);
    int tid = threadIdx.x;
    int wave = tid >> 6, lane = tid & 63, lq = lane & 15, quad = lane >> 4;

    __shared__ __align__(16) float strip[16 * SSTR];   // 35072 B; epilogue aliases it
    __shared__ __align__(16) int elist[16 * 64];       // 4096 B
    __shared__ float ebtl[12];
    __shared__ int cn_s[16];

    // ---- build: zero strip, stage CSR rows, per-head edge-bias table ----
    for (int i = tid; i < 16 * SSTR / 4; i += 256)
        ((float4*)strip)[i] = make_float4(0.f, 0.f, 0.f, 0.f);
    if (tid < 11) ebtl[tid] = ebt[tid * 8 + h];
    {
        int r = tid >> 4, j4 = (tid & 15) * 4;
        int qrow = qt * 16 + r;
        bool rv = (qrow >= 1) && (qrow < TT);
        size_t crow = (size_t)b * TT + (rv ? qrow : 0);
        *(int4*)&elist[r * 64 + j4] = *(const int4*)(ebuf + crow * ECAP + j4);
        if ((tid & 15) == 0) cn_s[r] = rv ? min(cnt[crow], ECAP) : 0;
    }
    __syncthreads();
    if (tid < 16) {                         // vnode column s==0 (valid q>0 rows only)
        int qrow = qt * 16 + tid;
        if (qrow >= 1 && qrow < TT) strip[tid * SSTR] = vnode[h];
    }
    {
        int r = tid >> 4;
        int cn = cn_s[r];
        for (int j = tid & 15; j < cn; j += 16) {
            int e = elist[r * 64 + j];
            atomicAdd(&strip[r * SSTR + (e & 0xFFFF)], ebtl[e >> 16]);
        }
    }
    __syncthreads();

    // ---- s-loop: wave w handles sp = w, w+4, ... (<17); 1-deep prefetch ----
    int qg = qt * 16 + lq;
    int qr = min(qg, TT - 1);
    short8 z8 = {0,0,0,0,0,0,0,0};
    const short* qhS = (const short*)qhr;
    const short* khS = (const short*)khr;
    short8 qf = z8;
    if (quad < 2)
        qf = *(const short8*)(qhS + ((size_t)bh * TT + qr) * DD + quad * 8);
    const short* vtS = (const short*)(vtr + (size_t)bh * DD * SP);

    floatx4 oacc = {0.f, 0.f, 0.f, 0.f};
    float lsum = 0.f;

    short8 af0c = z8, af1c = z8, vfc;
    {
        int sp = wave;
        int t0r = min(sp * 2 * 16 + lq, TT - 1);
        int t1r = min((sp * 2 + 1) * 16 + lq, TT - 1);
        if (quad < 2) {
            af0c = *(const short8*)(khS + ((size_t)bh * TT + t0r) * DD + quad * 8);
            af1c = *(const short8*)(khS + ((size_t)bh * TT + t1r) * DD + quad * 8);
        }
        vfc = *(const short8*)(vtS + (size_t)lq * SP + sp * 32 + quad * 8);
    }

    for (int sp = wave; sp < 17; sp += 4) {
        int spn = sp + 4;
        short8 af0n = z8, af1n = z8, vfn = z8;
        if (spn < 17) {
            int t0r = min(spn * 2 * 16 + lq, TT - 1);
            int t1r = min((spn * 2 + 1) * 16 + lq, TT - 1);
            if (quad < 2) {
                af0n = *(const short8*)(khS + ((size_t)bh * TT + t0r) * DD + quad * 8);
                af1n = *(const short8*)(khS + ((size_t)bh * TT + t1r) * DD + quad * 8);
            }
            vfn = *(const short8*)(vtS + (size_t)lq * SP + spn * 32 + quad * 8);
        }

        int roff = lq * SSTR + sp * 32 + quad * 4;
        float4 bia = *(const float4*)&strip[roff];
        float4 bib = *(const float4*)&strip[roff + 16];

        unsigned pw[2][2];
        #pragma unroll
        for (int t = 0; t < 2; ++t) {
            int st = sp * 2 + t;
            floatx4 cc4 = __builtin_amdgcn_mfma_f32_16x16x32_bf16(
                t ? af1c : af0c, qf, (floatx4){0.f, 0.f, 0.f, 0.f}, 0, 0, 0);
            float4 bi = t ? bib : bia;
            float biv[4] = {bi.x, bi.y, bi.z, bi.w};
            float pr[4];
            #pragma unroll
            for (int rg = 0; rg < 4; ++rg) {
                int s = st * 16 + quad * 4 + rg;
                float p = 0.f;
                if (s < TT) p = __expf(cc4[rg] + biv[rg]);
                lsum += p;
                pr[rg] = p;
            }
            pw[t][0] = (unsigned)f2bf(pr[0]) | ((unsigned)f2bf(pr[1]) << 16);
            pw[t][1] = (unsigned)f2bf(pr[2]) | ((unsigned)f2bf(pr[3]) << 16);
        }
        int srcA = lq + (((2 * quad) & 3) << 4);
        int srcB = lq + (((2 * quad + 1) & 3) << 4);
        int a00 = __shfl((int)pw[0][0], srcA, 64);
        int a01 = __shfl((int)pw[0][1], srcA, 64);
        int a10 = __shfl((int)pw[1][0], srcA, 64);
        int a11 = __shfl((int)pw[1][1], srcA, 64);
        int b00 = __shfl((int)pw[0][0], srcB, 64);
        int b01 = __shfl((int)pw[0][1], srcB, 64);
        int b10 = __shfl((int)pw[1][0], srcB, 64);
        int b11 = __shfl((int)pw[1][1], srcB, 64);
        union { int u[4]; short8 s8; } pu;
        bool lo = quad < 2;
        pu.u[0] = lo ? a00 : a10;
        pu.u[1] = lo ? a01 : a11;
        pu.u[2] = lo ? b00 : b10;
        pu.u[3] = lo ? b01 : b11;
        oacc = __builtin_amdgcn_mfma_f32_16x16x32_bf16(vfc, pu.s8, oacc, 0, 0, 0);

        af0c = af0n; af1c = af1n; vfc = vfn;
    }

    // ---- cross-wave reduce (4 waves) -> obf ----
    lsum += __shfl_xor(lsum, 16, 64);
    lsum += __shfl_xor(lsum, 32, 64);
    __syncthreads();                       // all strip reads done; reuse as arena
    float* redw = strip;
    float* lsumS = strip + 1088;
    #pragma unroll
    for (int rg = 0; rg < 4; ++rg)
        redw[wave * 272 + (quad * 4 + rg) * 17 + lq] = oacc[rg];
    if (quad == 0) lsumS[wave * 16 + lq] = lsum;
    __syncthreads();
    {
        int q = tid >> 4, d = tid & 15;
        float o = 0.f, L = 0.f;
        #pragma unroll
        for (int w = 0; w < 4; ++w) {
            o += redw[w * 272 + d * 17 + q];
            L += lsumS[w * 16 + q];
        }
        int qq = qt * 16 + q;
        if (qq < TT)
            obf[((size_t)(b * TT + qq)) * CC + h * DD + d] = f2bf(o / L);
    }
}

// ---------------- mega kernel (8 waves, 8-ROW tiles, 1040 blocks): o-proj+res+ln2+
//   ffn1+gelu+ffn2+res + (ln1next + QKVnext) or folded head on the last layer.
//   MFMA frames stay 16-row; local rows 8-15 are pad (clamped reads, guarded stores).
//   launch_bounds (512,4): VGPR budget 128 (lands ~64, spill-free); HW allows
//   4 co-resident blocks/CU at VGPR<=64 — grid provides 1040/256 = 4.06.
__global__ __launch_bounds__(512, 4) void mega_kernel(const ushort_t* __restrict__ obf,
                                                      const ushort_t* __restrict__ WtO,
                                                      const float* __restrict__ bo_,
                                                      const float* __restrict__ ln2g_,
                                                      const float* __restrict__ ln2b_,
                                                      const ushort_t* __restrict__ Wt1_,
                                                      const float* __restrict__ b1_,
                                                      const ushort_t* __restrict__ Wt2_,
                                                      const float* __restrict__ b2_,
                                                      const float* __restrict__ ln1g_,
                                                      const float* __restrict__ ln1b_,
                                                      const ushort_t* __restrict__ Wtq,
                                                      const float* __restrict__ bq_,
                                                      const ushort_t* __restrict__ Wtk,
                                                      const float* __restrict__ bk_,
                                                      const ushort_t* __restrict__ Wtv,
                                                      const float* __restrict__ bv_,
                                                      const float* __restrict__ nfg,
                                                      const float* __restrict__ nfb,
                                                      const float* __restrict__ Wc1,
                                                      const float* __restrict__ bc1,
                                                      const float* __restrict__ Wc2,
                                                      const float* __restrict__ bc2,
                                                      float* __restrict__ x_,
                                                      ushort_t* __restrict__ qhw,
                                                      ushort_t* __restrict__ khw,
                                                      ushort_t* __restrict__ vtw,
                                                      float* __restrict__ out,
                                                      int doQKV) {
    int qt = blockIdx.x, b = blockIdx.y;
    int tid = threadIdx.x;
    int wave = tid >> 6, lane = tid & 63, lq = lane & 15, quad = lane >> 4;

    __shared__ __align__(16) ushort_t hs[16 * 128];
    __shared__ __align__(16) ushort_t ms[16 * 512];
    __shared__ float sred[8][16][2];

    int t0 = qt * 8;                       // 8-row tile; rows 8-15 of frame are pad
    int c = wave * 16 + lq;
    float vv0[4];

    // ---- entry prefetch: x residuals (owned rows exact; pad rows race-tolerant) ----
    float xr[4];
    #pragma unroll
    for (int rg = 0; rg < 4; ++rg) {
        int t = t0 + quad * 4 + rg;
        xr[rg] = x_[((size_t)b * TT + min(t, TT - 1)) * CC + c];
    }

    // ---- stage 1: o-proj (16x16 frame per wave, K=128, A rows from global obf) + res + ln2 -> hs
    {
        const short* obS = (const short*)obf;
        size_t arow = (size_t)b * TT + min(t0 + lq, TT - 1);
        const short* W = (const short*)WtO;
        size_t rB = (size_t)c * CC;
        floatx4 a0 = {0.f,0.f,0.f,0.f};
        #pragma unroll
        for (int k0 = 0; k0 < CC; k0 += 32) {
            short8 af = *(const short8*)(obS + arow * CC + k0 + quad * 8);
            short8 b0 = *(const short8*)(W + rB + k0 + quad * 8);
            a0 = __builtin_amdgcn_mfma_f32_16x16x32_bf16(af, b0, a0, 0, 0, 0);
        }
        float bv0 = bo_[c];
        #pragma unroll
        for (int rg = 0; rg < 4; ++rg)
            vv0[rg] = a0[rg] + bv0 + xr[rg];
        #pragma unroll
        for (int rg = 0; rg < 4; ++rg) {
            float s1 = vv0[rg];
            float s2 = vv0[rg] * vv0[rg];
            #pragma unroll
            for (int m = 1; m < 16; m <<= 1) {
                s1 += __shfl_xor(s1, m, 64);
                s2 += __shfl_xor(s2, m, 64);
            }
            if (lq == 0) { sred[wave][quad*4+rg][0] = s1; sred[wave][quad*4+rg][1] = s2; }
        }
        __syncthreads();
        float g0 = ln2g_[c], lb0 = ln2b_[c];
        #pragma unroll
        for (int rg = 0; rg < 4; ++rg) {
            int row = quad * 4 + rg;
            float S1 = 0.f, S2 = 0.f;
            #pragma unroll
            for (int w = 0; w < 8; ++w) { S1 += sred[w][row][0]; S2 += sred[w][row][1]; }
            float mn = S1 * (1.0f/CC);
            float var = S2 * (1.0f/CC) - mn * mn;
            float rs = rsqrtf(var + 1e-5f);
            hs[swz(row, c, 128)] = f2bf((vv0[rg] - mn) * rs * g0 + lb0);
        }
    }
    __syncthreads();

    // ---- stage 2: ffn1 (wave covers mid cols wave*64..+63, K=128) + gelu -> ms ----
    {
        const short* hsS = (const short*)hs;
        const short* W = (const short*)Wt1_;
        #pragma unroll
        for (int nt = 0; nt < 4; ++nt) {
            int n = wave * 64 + nt * 16;
            size_t rB = (size_t)(n + lq) * CC;
            floatx4 a0 = {0.f,0.f,0.f,0.f};
            #pragma unroll
            for (int k0 = 0; k0 < CC; k0 += 32) {
                short8 af = *(const short8*)(hsS + swz(lq, k0 + quad * 8, 128));
                short8 b0 = *(const short8*)(W + rB + k0 + quad * 8);
                a0 = __builtin_amdgcn_mfma_f32_16x16x32_bf16(af, b0, a0, 0, 0, 0);
            }
            float bb0 = b1_[n + lq];
            #pragma unroll
            for (int rg = 0; rg < 4; ++rg)
                ms[swz(quad * 4 + rg, n + lq, 512)] = f2bf(gelu_exact(a0[rg] + bb0));
        }
    }
    __syncthreads();

    // ---- stage 3: ffn2 (16x16 frame per wave, K=512 from ms) + res ----
    float w0[4];
    {
        const short* msS = (const short*)ms;
        const short* W = (const short*)Wt2_;
        size_t rB = (size_t)c * FFN;
        floatx4 a0 = {0.f,0.f,0.f,0.f};
        #pragma unroll 8
        for (int k0 = 0; k0 < FFN; k0 += 32) {
            short8 af = *(const short8*)(msS + swz(lq, k0 + quad * 8, 512));
            short8 b0 = *(const short8*)(W + rB + k0 + quad * 8);
            a0 = __builtin_amdgcn_mfma_f32_16x16x32_bf16(af, b0, a0, 0, 0, 0);
        }
        float bv0 = b2_[c];
        #pragma unroll
        for (int rg = 0; rg < 4; ++rg) {
            int r8 = quad * 4 + rg;
            int t = t0 + r8;
            w0[rg] = a0[rg] + bv0 + vv0[rg];
            if (r8 < 8 && t < TT) x_[((size_t)b * TT + t) * CC + c] = w0[rg];
        }
    }

    if (doQKV) {
        // ln1(next layer) -> hs, then QKV into ping-pong buffers
        #pragma unroll
        for (int rg = 0; rg < 4; ++rg) {
            float s1 = w0[rg];
            float s2 = w0[rg] * w0[rg];
            #pragma unroll
            for (int m = 1; m < 16; m <<= 1) {
                s1 += __shfl_xor(s1, m, 64);
                s2 += __shfl_xor(s2, m, 64);
            }
            if (lq == 0) { sred[wave][quad*4+rg][0] = s1; sred[wave][quad*4+rg][1] = s2; }
        }
        __syncthreads();
        float g0 = ln1g_[c], lb0 = ln1b_[c];
        #pragma unroll
        for (int rg = 0; rg < 4; ++rg) {
            int row = quad * 4 + rg;
            float S1 = 0.f, S2 = 0.f;
            #pragma unroll
            for (int w = 0; w < 8; ++w) { S1 += sred[w][row][0]; S2 += sred[w][row][1]; }
            float mn = S1 * (1.0f/CC);
            float var = S2 * (1.0f/CC) - mn * mn;
            float rs = rsqrtf(var + 1e-5f);
            hs[swz(row, c, 128)] = f2bf((w0[rg] - mn) * rs * g0 + lb0);
        }
        __syncthreads();
        qkv_stage8(hs, Wtq, bq_, Wtk, bk_, Wtv, bv_, qhw, khw, vtw, b, t0, wave, lq, quad, 8);
        return;
    }

    // ---- last layer: folded head for the graph-token row (tile qt == 0, row 0) ----
    if (qt != 0) return;

    __syncthreads();                      // all waves done reading ms; reuse as scratch
    float* hrow = (float*)ms;             // 128
    float* xfs  = hrow + CC;              // 128
    float* c1s  = xfs + CC;               // 64
    float* red  = c1s + 64;               // 4
    if (quad == 0) hrow[c] = w0[0];       // row 0 of tile: quad*4+rg == 0
    __syncthreads();

    {
        int ct = tid;
        float v = 0.f, s1 = 0.f, s2 = 0.f;
        if (ct < CC) { v = hrow[ct]; s1 = v; s2 = v * v; }
        #pragma unroll
        for (int m = 32; m >= 1; m >>= 1) {
            s1 += __shfl_xor(s1, m, 64);
            s2 += __shfl_xor(s2, m, 64);
        }
        int w = ct >> 6;
        if (ct < CC && (ct & 63) == 0) { red[w*2] = s1; red[w*2+1] = s2; }
        __syncthreads();
        if (ct < CC) {
            float S1 = red[0] + red[2], S2 = red[1] + red[3];
            float mn = S1 * (1.0f/CC);
            float var = S2 * (1.0f/CC) - mn * mn;
            float rs = rsqrtf(var + 1e-5f);
            xfs[ct] = (v - mn) * rs * nfg[ct] + nfb[ct];
        }
        __syncthreads();
        if (ct < 64) {
            float acc = bc1[ct];
            #pragma unroll 4
            for (int k = 0; k < CC; ++k) acc = fmaf(xfs[k], Wc1[(size_t)k * 64 + ct], acc);
            c1s[ct] = gelu_exact(acc);
        }
        __syncthreads();
        if (ct < NCLS) {
            float acc = bc2[ct];
            #pragma unroll 4
            for (int j = 0; j < 64; ++j) acc = fmaf(c1s[j], Wc2[(size_t)j * NCLS + ct], acc);
            out[(size_t)b * NCLS + ct] = acc;
        }
    }
}

extern "C" void kernel_launch(void* const* d_in, const int* in_sizes, int n_in,
                              void* d_out, int out_size, void* d_ws, size_t ws_size,
                              hipStream_t stream) {
    const float* node_feats = (const float*)d_in[0];
    const int*   edge_index = (const int*)d_in[1];
    const int*   edge_attr  = (const int*)d_in[2];
    const float* W_node  = (const float*)d_in[4];
    const float* b_node  = (const float*)d_in[5];
    const float* g_token = (const float*)d_in[6];
    const float* ebt     = (const float*)d_in[7];
    const float* ide     = (const float*)d_in[8];
    const float* ode     = (const float*)d_in[9];
    const float* vnode   = (const float*)d_in[10];
    const float* Wq = (const float*)d_in[11];
    const float* bq = (const float*)d_in[12];
    const float* Wk = (const float*)d_in[13];
    const float* bk = (const float*)d_in[14];
    const float* Wv = (const float*)d_in[15];
    const float* bv = (const float*)d_in[16];
    const float* Wo = (const float*)d_in[17];
    const float* bo = (const float*)d_in[18];
    const float* ln1g = (const float*)d_in[19];
    const float* ln1b = (const float*)d_in[20];
    const float* ln2g = (const float*)d_in[21];
    const float* ln2b = (const float*)d_in[22];
    const float* W1 = (const float*)d_in[23];
    const float* b1 = (const float*)d_in[24];
    const float* W2 = (const float*)d_in[25];
    const float* b2 = (const float*)d_in[26];
    const float* nfg = (const float*)d_in[27];
    const float* nfb = (const float*)d_in[28];
    const float* Wc1 = (const float*)d_in[29];
    const float* bc1 = (const float*)d_in[30];
    const float* Wc2 = (const float*)d_in[31];
    const float* bc2 = (const float*)d_in[32];
    float* out = (float*)d_out;

    // ---- workspace (all chunks 16B-aligned); qh/kh/vt double-buffered ----
    char* base = (char*)d_ws;
    float* x      = (float*)base;     base += XSZ * 4;
    ushort_t* qh0 = (ushort_t*)base;  base += XSZ * 2;
    ushort_t* kh0 = (ushort_t*)base;  base += XSZ * 2;
    ushort_t* vt0 = (ushort_t*)base;  base += VTSZ * 2;
    ushort_t* qh1 = (ushort_t*)base;  base += XSZ * 2;
    ushort_t* kh1 = (ushort_t*)base;  base += XSZ * 2;
    ushort_t* vt1 = (ushort_t*)base;  base += VTSZ * 2;
    ushort_t* obf = (ushort_t*)base;  base += XSZ * 2;
    ushort_t* wtqkvo = (ushort_t*)base; base += (size_t)16 * 16384 * 2;
    ushort_t* wt1 = (ushort_t*)base;  base += (size_t)4 * 65536 * 2;
    ushort_t* wt2 = (ushort_t*)base;  base += (size_t)4 * 65536 * 2;
    int* deg_in  = (int*)base;        base += NNODES * 4;
    int* deg_out = (int*)base;        base += NNODES * 4;
    int* cnt     = (int*)base;        base += (size_t)ROWS * 4;
    int* ebuf    = (int*)base;        base += (size_t)ROWS * ECAP * 4;

    ushort_t* qhs[2] = {qh0, qh1};
    ushort_t* khs[2] = {kh0, kh1};
    ushort_t* vts[2] = {vt0, vt1};

    hipMemsetAsync(deg_in, 0, (size_t)(2 * NNODES + ROWS) * 4, stream);
    deg_csr_tr_kernel<<<512 + 192, 256, 0, stream>>>(
        edge_index, edge_attr, deg_in, deg_out, cnt, ebuf,
        Wq, Wk, Wv, Wo, W1, W2, wtqkvo, wt1, wt2);

    pre_kernel<<<528, 512, 0, stream>>>(
        node_feats, W_node, b_node, g_token, ide, ode, deg_in, deg_out,
        ln1g, ln1b, wtqkvo, bq, bk, bv, x, qh0, kh0, vt0);

    for (int l = 0; l < LL; ++l) {
        int rd = l & 1, wr = rd ^ 1;
        int ln = (l + 1) % LL;   // next layer (unused when l==LL-1)

        attn_kernel<<<dim3(33, BB * HH), 256, 0, stream>>>(
            qhs[rd], khs[rd], vts[rd], cnt, ebuf, ebt, vnode, obf);

        mega_kernel<<<dim3(65, BB), 512, 0, stream>>>(
            obf,
            wtqkvo + (size_t)(12 + l)*16384, bo + l*CC,
            ln2g + l*CC, ln2b + l*CC,
            wt1 + (size_t)l*65536, b1 + l*FFN,
            wt2 + (size_t)l*65536, b2 + l*CC,
            ln1g + ln*CC, ln1b + ln*CC,
            wtqkvo + (size_t)(0 + ln)*16384, bq + ln*CC,
            wtqkvo + (size_t)(4 + ln)*16384, bk + ln*CC,
            wtqkvo + (size_t)(8 + ln)*16384, bv + ln*CC,
            nfg, nfb, Wc1, bc1, Wc2, bc2,
            x, qhs[wr], khs[wr], vts[wr], out,
            (l < LL-1) ? 1 : 0);
    }
}

// Round 9
// 429.522 us; speedup vs baseline: 1.3115x; 1.2506x over previous
//
#include <hip/hip_runtime.h>
#include <hip/hip_bf16.h>

#define BB 16
#define NPG 512
#define CC 128
#define HH 8
#define LL 4
#define FFN 512
#define NCLS 4
#define DD 16
#define TT 513            // NPG + 1
#define EE 131072         // B * 8192
#define NNODES 8192       // B * NPG
#define ROWS (BB * TT)    // 8208 CSR rows keyed by (g, sl=query)
#define ECAP 64           // entries per bucket; Poisson(16), P(>=64) ~ 3e-22
#define SP 544            // padded s extent (34 tiles of 16)
#define SSTR 548          // dense strip stride (floats); 548 mod 32 = 4

static constexpr size_t XROWS = (size_t)BB * TT;   // 8208 (= 513 * 16 exactly)
static constexpr size_t XSZ   = XROWS * CC;        // 1,050,624
static constexpr size_t VTSZ  = (size_t)BB * HH * DD * SP;  // 1,114,112

typedef unsigned short ushort_t;
typedef __attribute__((ext_vector_type(8))) short short8;
typedef __attribute__((ext_vector_type(4))) float floatx4;

__device__ __forceinline__ float gelu_exact(float v) {
    return 0.5f * v * (1.0f + erff(v * 0.70710678118654752440f));
}
__device__ __forceinline__ ushort_t f2bf(float f) {
    union { float f; unsigned u; } c; c.f = f;
    unsigned u = c.u;
    return (ushort_t)((u + 0x7FFFu + ((u >> 16) & 1u)) >> 16);   // RNE
}
// XOR-swizzled LDS offset (16B granules); stride in shorts, multiple of 8
__device__ __forceinline__ int swz(int row, int col, int stride) {
    int kb = col >> 3;
    return row * stride + (((kb ^ (row & 7)) << 3) | (col & 7));
}

// ---- QKV stage (8-wave, 512 thr, per-graph tiles): hs -> qh, kh, vt ----
// qh/kh are per-head contiguous: [bh][t][16].
__device__ __forceinline__ void qkv_stage8(const ushort_t* hs,
                                           const ushort_t* Wtq, const float* bq_,
                                           const ushort_t* Wtk, const float* bk_,
                                           const ushort_t* Wtv, const float* bv_,
                                           ushort_t* qh, ushort_t* kh, ushort_t* vt,
                                           int b, int t0, int wave, int lq, int quad) {
    const short* hsS = (const short*)hs;
    int c = wave * 16 + lq;
    const short* Ws[3] = {(const short*)Wtq, (const short*)Wtk, (const short*)Wtv};
    const float* bs[3] = {bq_, bk_, bv_};
    size_t rB = (size_t)c * CC;

    #pragma unroll
    for (int m = 0; m < 3; ++m) {
        const short* W = Ws[m];
        floatx4 a0 = {0.f,0.f,0.f,0.f};
        #pragma unroll
        for (int k0 = 0; k0 < CC; k0 += 32) {
            short8 af = *(const short8*)(hsS + swz(lq, k0 + quad * 8, 128));
            short8 b0 = *(const short8*)(W + rB + k0 + quad * 8);
            a0 = __builtin_amdgcn_mfma_f32_16x16x32_bf16(af, b0, a0, 0, 0, 0);
        }
        float bv0 = bs[m][c];
        #pragma unroll
        for (int rg = 0; rg < 4; ++rg) {
            int t = t0 + quad * 4 + rg;
            if (t >= TT) continue;               // pad row: discard
            float v0 = a0[rg] + bv0;
            size_t hr = ((size_t)(b * HH + wave) * TT + t) * DD + lq;  // head=wave, d=lq
            if (m == 0) {        // Q: fold 1/sqrt(D)=0.25 (exact)
                qh[hr] = f2bf(v0 * 0.25f);
            } else if (m == 1) { // K
                kh[hr] = f2bf(v0);
            } else {             // V, written transposed VT[bh][d][s]
                vt[((size_t)(b * HH + wave) * DD + lq) * SP + t] = f2bf(v0);
            }
        }
    }
}

// ---- QKV stage (4-wave, 256 thr, straddling 16-row tile): hs -> qh, kh, vt ----
// wave covers cols n0..n0+31 (2 fragments); rows r = m0 + quad*4 + rg (all valid).
__device__ __forceinline__ void qkv_stage4(const ushort_t* hs,
                                           const ushort_t* Wtq, const float* bq_,
                                           const ushort_t* Wtk, const float* bk_,
                                           const ushort_t* Wtv, const float* bv_,
                                           ushort_t* qh, ushort_t* kh, ushort_t* vt,
                                           int m0, int wave, int lq, int quad) {
    const short* hsS = (const short*)hs;
    int n0 = wave * 32;
    int c0 = n0 + lq, c1 = n0 + 16 + lq;
    const short* Ws[3] = {(const short*)Wtq, (const short*)Wtk, (const short*)Wtv};
    const float* bs[3] = {bq_, bk_, bv_};
    size_t rB0 = (size_t)c0 * CC, rB1 = (size_t)c1 * CC;

    #pragma unroll
    for (int m = 0; m < 3; ++m) {
        const short* W = Ws[m];
        floatx4 a0 = {0.f,0.f,0.f,0.f}, a1 = a0;
        #pragma unroll
        for (int k0 = 0; k0 < CC; k0 += 32) {
            short8 af = *(const short8*)(hsS + swz(lq, k0 + quad * 8, 128));
            short8 b0 = *(const short8*)(W + rB0 + k0 + quad * 8);
            short8 b1 = *(const short8*)(W + rB1 + k0 + quad * 8);
            a0 = __builtin_amdgcn_mfma_f32_16x16x32_bf16(af, b0, a0, 0, 0, 0);
            a1 = __builtin_amdgcn_mfma_f32_16x16x32_bf16(af, b1, a1, 0, 0, 0);
        }
        float bv0 = bs[m][c0], bv1 = bs[m][c1];
        #pragma unroll
        for (int rg = 0; rg < 4; ++rg) {
            int r = m0 + quad * 4 + rg;        // 513x16 tiles: always < 8208, t < TT
            int bg = r / TT;
            int t = r - bg * TT;
            float v0 = a0[rg] + bv0;
            float v1 = a1[rg] + bv1;
            size_t h0 = ((size_t)(bg * HH + (c0 >> 4)) * TT + t) * DD + (c0 & 15);
            size_t h1 = ((size_t)(bg * HH + (c1 >> 4)) * TT + t) * DD + (c1 & 15);
            if (m == 0) {        // Q: fold 1/sqrt(D)=0.25 (exact)
                qh[h0] = f2bf(v0 * 0.25f);
                qh[h1] = f2bf(v1 * 0.25f);
            } else if (m == 1) { // K
                kh[h0] = f2bf(v0);
                kh[h1] = f2bf(v1);
            } else {             // V, written transposed VT[bh][d][s]
                vt[((size_t)(bg * HH + (c0 >> 4)) * DD + (c0 & 15)) * SP + t] = f2bf(v0);
                vt[((size_t)(bg * HH + (c1 >> 4)) * DD + (c1 & 15)) * SP + t] = f2bf(v1);
            }
        }
    }
}

// ---------------- merged: degree+CSR (blocks 0..511) | weight transpose (512..703) ----
__global__ __launch_bounds__(256) void deg_csr_tr_kernel(const int* __restrict__ ei,
                                                         const int* __restrict__ ea,
                                                         int* __restrict__ deg_in,
                                                         int* __restrict__ deg_out,
                                                         int* __restrict__ cnt,
                                                         int* __restrict__ ebuf,
                                                         const float* __restrict__ Wq,
                                                         const float* __restrict__ Wk,
                                                         const float* __restrict__ Wv,
                                                         const float* __restrict__ Wo,
                                                         const float* __restrict__ W1,
                                                         const float* __restrict__ W2,
                                                         ushort_t* __restrict__ wtqkvo,
                                                         ushort_t* __restrict__ wt1,
                                                         ushort_t* __restrict__ wt2) {
    int bid = blockIdx.x;
    int tid = threadIdx.x;
    if (bid < 512) {
        int e = bid * 256 + tid;
        int src = ei[e], dst = ei[EE + e];
        atomicAdd(&deg_out[src], 1);
        atomicAdd(&deg_in[dst], 1);
        int g = src >> 9;
        int sl = src - (g << 9) + 1;
        int dl = dst - (g << 9) + 1;
        int a = ea[e];
        a = (a < 0) ? 0 : (a > 9 ? 9 : a);
        a += 1;
        int row = g * TT + sl;
        int pos = atomicAdd(&cnt[row], 1);
        if (pos < ECAP) ebuf[(size_t)row * ECAP + pos] = dl | (a << 16);
        return;
    }
    // transpose tile z in [0,192): slot layout k*4+l (Q:0-3 K:4-7 V:8-11 O:12-15)
    int z = bid - 512;
    const float* src; ushort_t* dst; int K, N, tile;
    if (z < 64) {
        int zz = z >> 2; tile = z & 3;
        int k = zz >> 2, l = zz & 3;
        const float* s4[4] = {Wq, Wk, Wv, Wo};
        src = s4[k] + (size_t)l * CC * CC;
        dst = wtqkvo + (size_t)(k * 4 + l) * 16384;
        K = CC; N = CC;
    } else if (z < 128) {
        int l = (z - 64) >> 4; tile = (z - 64) & 15;
        src = W1 + (size_t)l * CC * FFN;
        dst = wt1 + (size_t)l * 65536;
        K = CC; N = FFN;
    } else {
        int l = (z - 128) >> 4; tile = (z - 128) & 15;
        src = W2 + (size_t)l * FFN * CC;
        dst = wt2 + (size_t)l * 65536;
        K = FFN; N = CC;
    }
    int tilesN = N >> 6;
    int k0 = (tile / tilesN) << 6;
    int n0 = (tile - (tile / tilesN) * tilesN) << 6;
    __shared__ float t[64][65];
    int c = tid & 63, rb = tid >> 6;
    #pragma unroll
    for (int kk = 0; kk < 64; kk += 4)
        t[kk + rb][c] = src[(size_t)(k0 + kk + rb) * N + n0 + c];
    __syncthreads();
    #pragma unroll
    for (int nn = 0; nn < 64; nn += 4)
        dst[(size_t)(n0 + nn + rb) * K + k0 + c] = f2bf(t[c][nn + rb]);
}

// ---------------- encode + ln1(L0) + QKV(L0): per-graph 16-row tiles, 512 thr ----
__global__ __launch_bounds__(512) void pre_kernel(const float* __restrict__ nf,
                                                  const float* __restrict__ Wn,
                                                  const float* __restrict__ bn,
                                                  const float* __restrict__ gt,
                                                  const float* __restrict__ ide,
                                                  const float* __restrict__ ode,
                                                  const int* __restrict__ deg_in,
                                                  const int* __restrict__ deg_out,
                                                  const float* __restrict__ ln1g_,
                                                  const float* __restrict__ ln1b_,
                                                  const ushort_t* __restrict__ wtqkvo,
                                                  const float* __restrict__ bq_,
                                                  const float* __restrict__ bk_,
                                                  const float* __restrict__ bv_,
                                                  float* __restrict__ x_,
                                                  ushort_t* __restrict__ qh,
                                                  ushort_t* __restrict__ kh,
                                                  ushort_t* __restrict__ vt) {
    int bid = blockIdx.x;
    int tid = threadIdx.x;
    int b = bid / 33, qt = bid - b * 33;
    int t0 = qt * 16;
    int wave = tid >> 6, lane = tid & 63, lq = lane & 15, quad = lane >> 4;

    __shared__ ushort_t hs[16 * 128];
    __shared__ float sred[8][16][2];

    int c = wave * 16 + lq;
    float w0[4];
    #pragma unroll
    for (int rg = 0; rg < 4; ++rg) {
        int t = t0 + quad * 4 + rg;
        int tc = min(t, TT - 1);            // clamp pad rows for reads
        float v0;
        if (tc == 0) {
            v0 = gt[c];
        } else {
            int i = b * NPG + tc - 1;
            float f0 = nf[i*3+0], f1 = nf[i*3+1], f2 = nf[i*3+2];
            v0 = bn[c] + f0*Wn[0*CC + c] + f1*Wn[1*CC + c] + f2*Wn[2*CC + c];
            int di = min(deg_in[i], 511);
            int dq = min(deg_out[i], 511);
            v0 += ide[(size_t)di * CC + c] + ode[(size_t)dq * CC + c];
        }
        if (t < TT) x_[((size_t)b * TT + t) * CC + c] = v0;
        w0[rg] = v0;
    }
    #pragma unroll
    for (int rg = 0; rg < 4; ++rg) {
        float s1 = w0[rg];
        float s2 = w0[rg] * w0[rg];
        #pragma unroll
        for (int m = 1; m < 16; m <<= 1) {
            s1 += __shfl_xor(s1, m, 64);
            s2 += __shfl_xor(s2, m, 64);
        }
        if (lq == 0) { sred[wave][quad*4+rg][0] = s1; sred[wave][quad*4+rg][1] = s2; }
    }
    __syncthreads();
    float g0 = ln1g_[c], lb0 = ln1b_[c];
    #pragma unroll
    for (int rg = 0; rg < 4; ++rg) {
        int row = quad * 4 + rg;
        float S1 = 0.f, S2 = 0.f;
        #pragma unroll
        for (int w = 0; w < 8; ++w) { S1 += sred[w][row][0]; S2 += sred[w][row][1]; }
        float mn = S1 * (1.0f/CC);
        float var = S2 * (1.0f/CC) - mn * mn;
        float rs = rsqrtf(var + 1e-5f);
        hs[swz(row, c, 128)] = f2bf((w0[rg] - mn) * rs * g0 + lb0);
    }
    __syncthreads();
    qkv_stage8(hs, wtqkvo, bq_,
               wtqkvo + (size_t)4 * 16384, bk_,
               wtqkvo + (size_t)8 * 16384, bv_,
               qh, kh, vt, b, t0, wave, lq, quad);
}

// ---------------- attention kernel: one block per (qt, b*h), 4 waves ----------------
//  dense single-head bias strip [16][548] f32 built ONCE per block, then fence-free
//  s-loop; Q/K fragments are per-head CONTIGUOUS (512B/fragment) loads from qh/kh.
__global__ __launch_bounds__(256, 4) void attn_kernel(const ushort_t* __restrict__ qhr,
                                                      const ushort_t* __restrict__ khr,
                                                      const ushort_t* __restrict__ vtr,
                                                      const int* __restrict__ cnt,
                                                      const int* __restrict__ ebuf,
                                                      const float* __restrict__ ebt,
                                                      const float* __restrict__ vnode,
                                                      ushort_t* __restrict__ obf) {
    int qt = blockIdx.x;
    int bh = blockIdx.y;
    int b = bh >> 3, h = bh & (HH - 1);
    int tid = threadIdx.x;
    int wave = tid >> 6, lane = tid & 63, lq = lane & 15, quad = lane >> 4;

    __shared__ __align__(16) float strip[16 * SSTR];   // 35072 B; epilogue aliases it
    __shared__ __align__(16) int elist[16 * 64];       // 4096 B
    __shared__ float ebtl[12];
    __shared__ int cn_s[16];

    // ---- build: zero strip, stage CSR rows, per-head edge-bias table ----
    for (int i = tid; i < 16 * SSTR / 4; i += 256)
        ((float4*)strip)[i] = make_float4(0.f, 0.f, 0.f, 0.f);
    if (tid < 11) ebtl[tid] = ebt[tid * 8 + h];
    {
        int r = tid >> 4, j4 = (tid & 15) * 4;
        int qrow = qt * 16 + r;
        bool rv = (qrow >= 1) && (qrow < TT);
        size_t crow = (size_t)b * TT + (rv ? qrow : 0);
        *(int4*)&elist[r * 64 + j4] = *(const int4*)(ebuf + crow * ECAP + j4);
        if ((tid & 15) == 0) cn_s[r] = rv ? min(cnt[crow], ECAP) : 0;
    }
    __syncthreads();
    if (tid < 16) {                         // vnode column s==0 (valid q>0 rows only)
        int qrow = qt * 16 + tid;
        if (qrow >= 1 && qrow < TT) strip[tid * SSTR] = vnode[h];
    }
    {
        int r = tid >> 4;
        int cn = cn_s[r];
        for (int j = tid & 15; j < cn; j += 16) {
            int e = elist[r * 64 + j];
            atomicAdd(&strip[r * SSTR + (e & 0xFFFF)], ebtl[e >> 16]);
        }
    }
    __syncthreads();

    // ---- s-loop: wave w handles sp = w, w+4, ... (<17); 1-deep prefetch ----
    int qg = qt * 16 + lq;
    int qr = min(qg, TT - 1);
    short8 z8 = {0,0,0,0,0,0,0,0};
    const short* qhS = (const short*)qhr;
    const short* khS = (const short*)khr;
    short8 qf = z8;
    if (quad < 2)
        qf = *(const short8*)(qhS + ((size_t)bh * TT + qr) * DD + quad * 8);
    const short* vtS = (const short*)(vtr + (size_t)bh * DD * SP);

    floatx4 oacc = {0.f, 0.f, 0.f, 0.f};
    float lsum = 0.f;

    short8 af0c = z8, af1c = z8, vfc;
    {
        int sp = wave;
        int t0r = min(sp * 2 * 16 + lq, TT - 1);
        int t1r = min((sp * 2 + 1) * 16 + lq, TT - 1);
        if (quad < 2) {
            af0c = *(const short8*)(khS + ((size_t)bh * TT + t0r) * DD + quad * 8);
            af1c = *(const short8*)(khS + ((size_t)bh * TT + t1r) * DD + quad * 8);
        }
        vfc = *(const short8*)(vtS + (size_t)lq * SP + sp * 32 + quad * 8);
    }

    for (int sp = wave; sp < 17; sp += 4) {
        int spn = sp + 4;
        short8 af0n = z8, af1n = z8, vfn = z8;
        if (spn < 17) {
            int t0r = min(spn * 2 * 16 + lq, TT - 1);
            int t1r = min((spn * 2 + 1) * 16 + lq, TT - 1);
            if (quad < 2) {
                af0n = *(const short8*)(khS + ((size_t)bh * TT + t0r) * DD + quad * 8);
                af1n = *(const short8*)(khS + ((size_t)bh * TT + t1r) * DD + quad * 8);
            }
            vfn = *(const short8*)(vtS + (size_t)lq * SP + spn * 32 + quad * 8);
        }

        int roff = lq * SSTR + sp * 32 + quad * 4;
        float4 bia = *(const float4*)&strip[roff];
        float4 bib = *(const float4*)&strip[roff + 16];

        unsigned pw[2][2];
        #pragma unroll
        for (int t = 0; t < 2; ++t) {
            int st = sp * 2 + t;
            floatx4 cc4 = __builtin_amdgcn_mfma_f32_16x16x32_bf16(
                t ? af1c : af0c, qf, (floatx4){0.f, 0.f, 0.f, 0.f}, 0, 0, 0);
            float4 bi = t ? bib : bia;
            float biv[4] = {bi.x, bi.y, bi.z, bi.w};
            float pr[4];
            #pragma unroll
            for (int rg = 0; rg < 4; ++rg) {
                int s = st * 16 + quad * 4 + rg;
                float p = 0.f;
                if (s < TT) p = __expf(cc4[rg] + biv[rg]);
                lsum += p;
                pr[rg] = p;
            }
            pw[t][0] = (unsigned)f2bf(pr[0]) | ((unsigned)f2bf(pr[1]) << 16);
            pw[t][1] = (unsigned)f2bf(pr[2]) | ((unsigned)f2bf(pr[3]) << 16);
        }
        int srcA = lq + (((2 * quad) & 3) << 4);
        int srcB = lq + (((2 * quad + 1) & 3) << 4);
        int a00 = __shfl((int)pw[0][0], srcA, 64);
        int a01 = __shfl((int)pw[0][1], srcA, 64);
        int a10 = __shfl((int)pw[1][0], srcA, 64);
        int a11 = __shfl((int)pw[1][1], srcA, 64);
        int b00 = __shfl((int)pw[0][0], srcB, 64);
        int b01 = __shfl((int)pw[0][1], srcB, 64);
        int b10 = __shfl((int)pw[1][0], srcB, 64);
        int b11 = __shfl((int)pw[1][1], srcB, 64);
        union { int u[4]; short8 s8; } pu;
        bool lo = quad < 2;
        pu.u[0] = lo ? a00 : a10;
        pu.u[1] = lo ? a01 : a11;
        pu.u[2] = lo ? b00 : b10;
        pu.u[3] = lo ? b01 : b11;
        oacc = __builtin_amdgcn_mfma_f32_16x16x32_bf16(vfc, pu.s8, oacc, 0, 0, 0);

        af0c = af0n; af1c = af1n; vfc = vfn;
    }

    // ---- cross-wave reduce (4 waves) -> obf ----
    lsum += __shfl_xor(lsum, 16, 64);
    lsum += __shfl_xor(lsum, 32, 64);
    __syncthreads();                       // all strip reads done; reuse as arena
    float* redw = strip;
    float* lsumS = strip + 1088;
    #pragma unroll
    for (int rg = 0; rg < 4; ++rg)
        redw[wave * 272 + (quad * 4 + rg) * 17 + lq] = oacc[rg];
    if (quad == 0) lsumS[wave * 16 + lq] = lsum;
    __syncthreads();
    {
        int q = tid >> 4, d = tid & 15;
        float o = 0.f, L = 0.f;
        #pragma unroll
        for (int w = 0; w < 4; ++w) {
            o += redw[w * 272 + d * 17 + q];
            L += lsumS[w * 16 + q];
        }
        int qq = qt * 16 + q;
        if (qq < TT)
            obf[((size_t)(b * TT + qq)) * CC + h * DD + d] = f2bf(o / L);
    }
}

// ---------------- mega kernel (4 waves, 256 thr, 513 straddling 16-row tiles):
//   o-proj+res+ln2+ffn1+gelu+ffn2+res + (ln1next+QKVnext) or folded head (last layer).
//   launch_bounds (256,4): 4 blocks/CU co-resident -> 4 independent stage chains/CU.
__global__ __launch_bounds__(256, 4) void mega_kernel(const ushort_t* __restrict__ obf,
                                                      const ushort_t* __restrict__ WtO,
                                                      const float* __restrict__ bo_,
                                                      const float* __restrict__ ln2g_,
                                                      const float* __restrict__ ln2b_,
                                                      const ushort_t* __restrict__ Wt1_,
                                                      const float* __restrict__ b1_,
                                                      const ushort_t* __restrict__ Wt2_,
                                                      const float* __restrict__ b2_,
                                                      const float* __restrict__ ln1g_,
                                                      const float* __restrict__ ln1b_,
                                                      const ushort_t* __restrict__ Wtq,
                                                      const float* __restrict__ bq_,
                                                      const ushort_t* __restrict__ Wtk,
                                                      const float* __restrict__ bk_,
                                                      const ushort_t* __restrict__ Wtv,
                                                      const float* __restrict__ bv_,
                                                      const float* __restrict__ nfg,
                                                      const float* __restrict__ nfb,
                                                      const float* __restrict__ Wc1,
                                                      const float* __restrict__ bc1,
                                                      const float* __restrict__ Wc2,
                                                      const float* __restrict__ bc2,
                                                      float* __restrict__ x_,
                                                      ushort_t* __restrict__ qhw,
                                                      ushort_t* __restrict__ khw,
                                                      ushort_t* __restrict__ vtw,
                                                      float* __restrict__ out,
                                                      int doQKV) {
    int m0 = blockIdx.x * 16;
    int tid = threadIdx.x;
    int wave = tid >> 6, lane = tid & 63, lq = lane & 15, quad = lane >> 4;

    __shared__ __align__(16) ushort_t hs[16 * 128];
    __shared__ __align__(16) ushort_t ms[16 * 512];
    __shared__ float sred[4][16][2];

    int n0 = wave * 32;
    int c0 = n0 + lq, c1 = n0 + 16 + lq;
    float vv0[4], vv1[4];

    // ---- entry prefetch: x residuals (rows always valid: 513x16 tiles exact) ----
    float xr0[4], xr1[4];
    #pragma unroll
    for (int rg = 0; rg < 4; ++rg) {
        int r = m0 + quad * 4 + rg;
        xr0[rg] = x_[(size_t)r * CC + c0];
        xr1[rg] = x_[(size_t)r * CC + c1];
    }

    // ---- stage 1: o-proj (16x32 per wave, K=128, A rows from global obf) + res + ln2 -> hs
    {
        const short* obS = (const short*)obf;
        size_t rowA = (size_t)(m0 + lq) * CC;
        const short* W = (const short*)WtO;
        size_t rB0 = (size_t)c0 * CC, rB1 = (size_t)c1 * CC;
        floatx4 a0 = {0.f,0.f,0.f,0.f}, a1 = a0;
        #pragma unroll
        for (int k0 = 0; k0 < CC; k0 += 32) {
            short8 af = *(const short8*)(obS + rowA + k0 + quad * 8);
            short8 b0 = *(const short8*)(W + rB0 + k0 + quad * 8);
            short8 b1 = *(const short8*)(W + rB1 + k0 + quad * 8);
            a0 = __builtin_amdgcn_mfma_f32_16x16x32_bf16(af, b0, a0, 0, 0, 0);
            a1 = __builtin_amdgcn_mfma_f32_16x16x32_bf16(af, b1, a1, 0, 0, 0);
        }
        float bv0 = bo_[c0], bv1 = bo_[c1];
        #pragma unroll
        for (int rg = 0; rg < 4; ++rg) {
            vv0[rg] = a0[rg] + bv0 + xr0[rg];
            vv1[rg] = a1[rg] + bv1 + xr1[rg];
        }
        #pragma unroll
        for (int rg = 0; rg < 4; ++rg) {
            float s1 = vv0[rg] + vv1[rg];
            float s2 = vv0[rg]*vv0[rg] + vv1[rg]*vv1[rg];
            #pragma unroll
            for (int m = 1; m < 16; m <<= 1) {
                s1 += __shfl_xor(s1, m, 64);
                s2 += __shfl_xor(s2, m, 64);
            }
            if (lq == 0) { sred[wave][quad*4+rg][0] = s1; sred[wave][quad*4+rg][1] = s2; }
        }
        __syncthreads();
        float g0 = ln2g_[c0], g1 = ln2g_[c1], lb0 = ln2b_[c0], lb1 = ln2b_[c1];
        #pragma unroll
        for (int rg = 0; rg < 4; ++rg) {
            int row = quad * 4 + rg;
            float S1 = sred[0][row][0] + sred[1][row][0] + sred[2][row][0] + sred[3][row][0];
            float S2 = sred[0][row][1] + sred[1][row][1] + sred[2][row][1] + sred[3][row][1];
            float mn = S1 * (1.0f/CC);
            float var = S2 * (1.0f/CC) - mn * mn;
            float rs = rsqrtf(var + 1e-5f);
            hs[swz(row, c0, 128)] = f2bf((vv0[rg] - mn) * rs * g0 + lb0);
            hs[swz(row, c1, 128)] = f2bf((vv1[rg] - mn) * rs * g1 + lb1);
        }
    }
    __syncthreads();

    // ---- stage 2: ffn1 (wave covers mid cols wave*128..+127, K=128) + gelu -> ms ----
    {
        const short* hsS = (const short*)hs;
        const short* W = (const short*)Wt1_;
        #pragma unroll
        for (int nt = 0; nt < 4; ++nt) {
            int n = wave * 128 + nt * 32;
            size_t rB0 = (size_t)(n + lq) * CC, rB1 = (size_t)(n + 16 + lq) * CC;
            floatx4 a0 = {0.f,0.f,0.f,0.f}, a1 = a0;
            #pragma unroll
            for (int k0 = 0; k0 < CC; k0 += 32) {
                short8 af = *(const short8*)(hsS + swz(lq, k0 + quad * 8, 128));
                short8 b0 = *(const short8*)(W + rB0 + k0 + quad * 8);
                short8 b1 = *(const short8*)(W + rB1 + k0 + quad * 8);
                a0 = __builtin_amdgcn_mfma_f32_16x16x32_bf16(af, b0, a0, 0, 0, 0);
                a1 = __builtin_amdgcn_mfma_f32_16x16x32_bf16(af, b1, a1, 0, 0, 0);
            }
            float bb0 = b1_[n + lq], bb1 = b1_[n + 16 + lq];
            #pragma unroll
            for (int rg = 0; rg < 4; ++rg) {
                int row = quad * 4 + rg;
                ms[swz(row, n + lq, 512)]      = f2bf(gelu_exact(a0[rg] + bb0));
                ms[swz(row, n + 16 + lq, 512)] = f2bf(gelu_exact(a1[rg] + bb1));
            }
        }
    }
    __syncthreads();

    // ---- stage 3: ffn2 (16x32 per wave, K=512 from ms) + res ----
    float w0[4], w1[4];
    {
        const short* msS = (const short*)ms;
        const short* W = (const short*)Wt2_;
        size_t rB0 = (size_t)c0 * FFN, rB1 = (size_t)c1 * FFN;
        floatx4 a0 = {0.f,0.f,0.f,0.f}, a1 = a0;
        #pragma unroll 8
        for (int k0 = 0; k0 < FFN; k0 += 32) {
            short8 af = *(const short8*)(msS + swz(lq, k0 + quad * 8, 512));
            short8 b0 = *(const short8*)(W + rB0 + k0 + quad * 8);
            short8 b1 = *(const short8*)(W + rB1 + k0 + quad * 8);
            a0 = __builtin_amdgcn_mfma_f32_16x16x32_bf16(af, b0, a0, 0, 0, 0);
            a1 = __builtin_amdgcn_mfma_f32_16x16x32_bf16(af, b1, a1, 0, 0, 0);
        }
        float bv0 = b2_[c0], bv1 = b2_[c1];
        #pragma unroll
        for (int rg = 0; rg < 4; ++rg) {
            int r = m0 + quad * 4 + rg;
            w0[rg] = a0[rg] + bv0 + vv0[rg];
            w1[rg] = a1[rg] + bv1 + vv1[rg];
            x_[(size_t)r * CC + c0] = w0[rg];
            x_[(size_t)r * CC + c1] = w1[rg];
        }
    }

    if (doQKV) {
        // ln1(next layer) -> hs, then QKV into ping-pong buffers
        #pragma unroll
        for (int rg = 0; rg < 4; ++rg) {
            float s1 = w0[rg] + w1[rg];
            float s2 = w0[rg]*w0[rg] + w1[rg]*w1[rg];
            #pragma unroll
            for (int m = 1; m < 16; m <<= 1) {
                s1 += __shfl_xor(s1, m, 64);
                s2 += __shfl_xor(s2, m, 64);
            }
            if (lq == 0) { sred[wave][quad*4+rg][0] = s1; sred[wave][quad*4+rg][1] = s2; }
        }
        __syncthreads();
        float g0 = ln1g_[c0], g1 = ln1g_[c1], lb0 = ln1b_[c0], lb1 = ln1b_[c1];
        #pragma unroll
        for (int rg = 0; rg < 4; ++rg) {
            int row = quad * 4 + rg;
            float S1 = sred[0][row][0] + sred[1][row][0] + sred[2][row][0] + sred[3][row][0];
            float S2 = sred[0][row][1] + sred[1][row][1] + sred[2][row][1] + sred[3][row][1];
            float mn = S1 * (1.0f/CC);
            float var = S2 * (1.0f/CC) - mn * mn;
            float rs = rsqrtf(var + 1e-5f);
            hs[swz(row, c0, 128)] = f2bf((w0[rg] - mn) * rs * g0 + lb0);
            hs[swz(row, c1, 128)] = f2bf((w1[rg] - mn) * rs * g1 + lb1);
        }
        __syncthreads();
        qkv_stage4(hs, Wtq, bq_, Wtk, bk_, Wtv, bv_, qhw, khw, vtw, m0, wave, lq, quad);
        return;
    }

    // ---- last layer: folded head for the graph-token row in this tile (if any) ----
    int gb = (m0 + TT - 1) / TT;          // candidate graph whose token row >= m0
    int rgt = gb * TT;
    if (gb >= BB || rgt >= m0 + 16) return;
    int hb = rgt - m0;                    // row within tile

    __syncthreads();                      // all waves done reading ms; reuse as scratch
    float* hrow = (float*)ms;             // 128
    float* xfs  = hrow + CC;              // 128
    float* c1s  = xfs + CC;               // 64
    float* red  = c1s + 64;               // 4
    #pragma unroll
    for (int rg = 0; rg < 4; ++rg) {
        if (quad * 4 + rg == hb) { hrow[c0] = w0[rg]; hrow[c1] = w1[rg]; }
    }
    __syncthreads();

    {
        int c = tid;
        float v = 0.f, s1 = 0.f, s2 = 0.f;
        if (c < CC) { v = hrow[c]; s1 = v; s2 = v * v; }
        #pragma unroll
        for (int m = 32; m >= 1; m >>= 1) {
            s1 += __shfl_xor(s1, m, 64);
            s2 += __shfl_xor(s2, m, 64);
        }
        int w = c >> 6;
        if (c < CC && (c & 63) == 0) { red[w*2] = s1; red[w*2+1] = s2; }
        __syncthreads();
        if (c < CC) {
            float S1 = red[0] + red[2], S2 = red[1] + red[3];
            float mn = S1 * (1.0f/CC);
            float var = S2 * (1.0f/CC) - mn * mn;
            float rs = rsqrtf(var + 1e-5f);
            xfs[c] = (v - mn) * rs * nfg[c] + nfb[c];
        }
        __syncthreads();
        if (c < 64) {
            float acc = bc1[c];
            #pragma unroll 4
            for (int k = 0; k < CC; ++k) acc = fmaf(xfs[k], Wc1[(size_t)k * 64 + c], acc);
            c1s[c] = gelu_exact(acc);
        }
        __syncthreads();
        if (c < NCLS) {
            float acc = bc2[c];
            #pragma unroll 4
            for (int j = 0; j < 64; ++j) acc = fmaf(c1s[j], Wc2[(size_t)j * NCLS + c], acc);
            out[(size_t)gb * NCLS + c] = acc;
        }
    }
}

extern "C" void kernel_launch(void* const* d_in, const int* in_sizes, int n_in,
                              void* d_out, int out_size, void* d_ws, size_t ws_size,
                              hipStream_t stream) {
    const float* node_feats = (const float*)d_in[0];
    const int*   edge_index = (const int*)d_in[1];
    const int*   edge_attr  = (const int*)d_in[2];
    const float* W_node  = (const float*)d_in[4];
    const float* b_node  = (const float*)d_in[5];
    const float* g_token = (const float*)d_in[6];
    const float* ebt     = (const float*)d_in[7];
    const float* ide     = (const float*)d_in[8];
    const float* ode     = (const float*)d_in[9];
    const float* vnode   = (const float*)d_in[10];
    const float* Wq = (const float*)d_in[11];
    const float* bq = (const float*)d_in[12];
    const float* Wk = (const float*)d_in[13];
    const float* bk = (const float*)d_in[14];
    const float* Wv = (const float*)d_in[15];
    const float* bv = (const float*)d_in[16];
    const float* Wo = (const float*)d_in[17];
    const float* bo = (const float*)d_in[18];
    const float* ln1g = (const float*)d_in[19];
    const float* ln1b = (const float*)d_in[20];
    const float* ln2g = (const float*)d_in[21];
    const float* ln2b = (const float*)d_in[22];
    const float* W1 = (const float*)d_in[23];
    const float* b1 = (const float*)d_in[24];
    const float* W2 = (const float*)d_in[25];
    const float* b2 = (const float*)d_in[26];
    const float* nfg = (const float*)d_in[27];
    const float* nfb = (const float*)d_in[28];
    const float* Wc1 = (const float*)d_in[29];
    const float* bc1 = (const float*)d_in[30];
    const float* Wc2 = (const float*)d_in[31];
    const float* bc2 = (const float*)d_in[32];
    float* out = (float*)d_out;

    // ---- workspace (all chunks 16B-aligned); qh/kh/vt double-buffered ----
    char* base = (char*)d_ws;
    float* x      = (float*)base;     base += XSZ * 4;
    ushort_t* qh0 = (ushort_t*)base;  base += XSZ * 2;
    ushort_t* kh0 = (ushort_t*)base;  base += XSZ * 2;
    ushort_t* vt0 = (ushort_t*)base;  base += VTSZ * 2;
    ushort_t* qh1 = (ushort_t*)base;  base += XSZ * 2;
    ushort_t* kh1 = (ushort_t*)base;  base += XSZ * 2;
    ushort_t* vt1 = (ushort_t*)base;  base += VTSZ * 2;
    ushort_t* obf = (ushort_t*)base;  base += XSZ * 2;
    ushort_t* wtqkvo = (ushort_t*)base; base += (size_t)16 * 16384 * 2;
    ushort_t* wt1 = (ushort_t*)base;  base += (size_t)4 * 65536 * 2;
    ushort_t* wt2 = (ushort_t*)base;  base += (size_t)4 * 65536 * 2;
    int* deg_in  = (int*)base;        base += NNODES * 4;
    int* deg_out = (int*)base;        base += NNODES * 4;
    int* cnt     = (int*)base;        base += (size_t)ROWS * 4;
    int* ebuf    = (int*)base;        base += (size_t)ROWS * ECAP * 4;

    ushort_t* qhs[2] = {qh0, qh1};
    ushort_t* khs[2] = {kh0, kh1};
    ushort_t* vts[2] = {vt0, vt1};

    hipMemsetAsync(deg_in, 0, (size_t)(2 * NNODES + ROWS) * 4, stream);
    deg_csr_tr_kernel<<<512 + 192, 256, 0, stream>>>(
        edge_index, edge_attr, deg_in, deg_out, cnt, ebuf,
        Wq, Wk, Wv, Wo, W1, W2, wtqkvo, wt1, wt2);

    pre_kernel<<<528, 512, 0, stream>>>(
        node_feats, W_node, b_node, g_token, ide, ode, deg_in, deg_out,
        ln1g, ln1b, wtqkvo, bq, bk, bv, x, qh0, kh0, vt0);

    const int MT16 = (int)(XROWS / 16);   // 513 straddling 16-row tiles (exact)

    for (int l = 0; l < LL; ++l) {
        int rd = l & 1, wr = rd ^ 1;
        int ln = (l + 1) % LL;   // next layer (unused when l==LL-1)

        attn_kernel<<<dim3(33, BB * HH), 256, 0, stream>>>(
            qhs[rd], khs[rd], vts[rd], cnt, ebuf, ebt, vnode, obf);

        mega_kernel<<<MT16, 256, 0, stream>>>(
            obf,
            wtqkvo + (size_t)(12 + l)*16384, bo + l*CC,
            ln2g + l*CC, ln2b + l*CC,
            wt1 + (size_t)l*65536, b1 + l*FFN,
            wt2 + (size_t)l*65536, b2 + l*CC,
            ln1g + ln*CC, ln1b + ln*CC,
            wtqkvo + (size_t)(0 + ln)*16384, bq + ln*CC,
            wtqkvo + (size_t)(4 + ln)*16384, bk + ln*CC,
            wtqkvo + (size_t)(8 + ln)*16384, bv + ln*CC,
            nfg, nfb, Wc1, bc1, Wc2, bc2,
            x, qhs[wr], khs[wr], vts[wr], out,
            (l < LL-1) ? 1 : 0);
    }
}